// Round 1
// baseline (3404.762 us; speedup 1.0000x reference)
//
#include <hip/hip_runtime.h>
#include <math.h>

constexpr int NV   = 100000;
constexpr int NEg  = 20000;
constexpr int NNZp = 1600000;
constexpr int NF   = 128;
constexpr int NH   = 64;
constexpr int NC   = 40;

// ---------------- counts: cnt[e] += 1 per incidence ----------------
__global__ __launch_bounds__(256) void count_kernel(const int* __restrict__ edges,
                                                    float* __restrict__ cnt) {
    int k = blockIdx.x * 256 + threadIdx.x;
    if (k < NNZp) atomicAdd(&cnt[edges[k]], 1.0f);
}

// scaleE[e] = degE[e] / max(cnt[e],1)   (in-place on cnt buffer)
__global__ __launch_bounds__(256) void scale_kernel(const float* __restrict__ degE,
                                                    float* __restrict__ scaleE) {
    int e = blockIdx.x * 256 + threadIdx.x;
    if (e < NEg) {
        float c = scaleE[e];
        c = c < 1.0f ? 1.0f : c;
        scaleE[e] = degE[e] / c;
    }
}

// ---------------- X = relu(x @ W0 + b0); X0 = X ----------------
// wave-per-row, W0 (128x64 = 32KB) in LDS
__global__ __launch_bounds__(256) void gemm0_kernel(const float* __restrict__ x,
                                                    const float* __restrict__ W0,
                                                    const float* __restrict__ b0,
                                                    float* __restrict__ X,
                                                    float* __restrict__ X0) {
    __shared__ float w[NF * NH];
    __shared__ float xs[4][NF];
    const int lane = threadIdx.x & 63;
    const int wid  = threadIdx.x >> 6;
    for (int i = threadIdx.x; i < NF * NH; i += 256) w[i] = W0[i];
    const int row = blockIdx.x * 4 + wid;   // grid = NV/4 exactly
    xs[wid][lane]      = x[row * NF + lane];
    xs[wid][lane + 64] = x[row * NF + 64 + lane];
    __syncthreads();
    float acc = b0[lane];
#pragma unroll 8
    for (int j = 0; j < NF; ++j) acc += xs[wid][j] * w[j * NH + lane];
    float r = acc > 0.f ? acc : 0.f;
    X[row * NH + lane]  = r;
    X0[row * NH + lane] = r;
}

// ---------------- vertex -> edge scatter: Xe[e] += X[v] ----------------
// one wave per incidence pair, lane = feature
__global__ __launch_bounds__(256) void scatter_ve(const int* __restrict__ vertex,
                                                  const int* __restrict__ edges,
                                                  const float* __restrict__ X,
                                                  float* __restrict__ Xe) {
    unsigned tid = blockIdx.x * 256u + threadIdx.x;
    int k = (int)(tid >> 6);
    int f = (int)(tid & 63u);
    if (k < NNZp) {
        int v = vertex[k];
        int e = edges[k];
        atomicAdd(&Xe[e * NH + f], X[v * NH + f]);
    }
}

// Xe *= scaleE (row-wise)
__global__ __launch_bounds__(256) void xe_scale(float* __restrict__ Xe,
                                                const float* __restrict__ scaleE) {
    int t = blockIdx.x * 256 + threadIdx.x;
    if (t < NEg * NH) Xe[t] *= scaleE[t >> 6];
}

// ---------------- edge -> vertex scatter: Xv[v] += Xe[e] ----------------
__global__ __launch_bounds__(256) void scatter_ev(const int* __restrict__ vertex,
                                                  const int* __restrict__ edges,
                                                  const float* __restrict__ Xe,
                                                  float* __restrict__ Xv) {
    unsigned tid = blockIdx.x * 256u + threadIdx.x;
    int k = (int)(tid >> 6);
    int f = (int)(tid & 63u);
    if (k < NNZp) {
        int e = edges[k];
        int v = vertex[k];
        atomicAdd(&Xv[v * NH + f], Xe[e * NH + f]);
    }
}

// ---------------- per-vertex: degV, l2-normalize, residual, 64x64 GEMM, relu ----
__global__ __launch_bounds__(256) void vertex_update(const float* __restrict__ Xv,
                                                     const float* __restrict__ degV,
                                                     const float* __restrict__ X0,
                                                     const float* __restrict__ Wl,
                                                     float* __restrict__ X,
                                                     float beta) {
    __shared__ float w[NH * NH];     // 16 KB
    __shared__ float xis[4][NH];
    const int lane = threadIdx.x & 63;
    const int wid  = threadIdx.x >> 6;
    for (int i = threadIdx.x; i < NH * NH; i += 256) w[i] = Wl[i];
    const int v = blockIdx.x * 4 + wid;   // grid = NV/4 exactly
    float xv = Xv[v * NH + lane] * degV[v];
    float sq = xv * xv;
#pragma unroll
    for (int o = 32; o; o >>= 1) sq += __shfl_xor(sq, o);
    float norm = sqrtf(sq);
    float xn = norm > 0.f ? xv / norm : 0.f;
    float xi = 0.9f * xn + 0.1f * X0[v * NH + lane];
    xis[wid][lane] = xi;
    __syncthreads();
    float acc = 0.f;
#pragma unroll 8
    for (int j = 0; j < NH; ++j) acc += xis[wid][j] * w[j * NH + lane];
    float outv = (1.f - beta) * xi + beta * acc;
    X[v * NH + lane] = outv > 0.f ? outv : 0.f;
}

// ---------------- logits = X @ Wout + bout ; log_softmax ----------------
__global__ __launch_bounds__(256) void output_kernel(const float* __restrict__ X,
                                                     const float* __restrict__ Wout,
                                                     const float* __restrict__ bout,
                                                     float* __restrict__ out) {
    __shared__ float w[NH * NC];     // 10.24 KB
    __shared__ float xs[4][NH];
    const int lane = threadIdx.x & 63;
    const int wid  = threadIdx.x >> 6;
    for (int i = threadIdx.x; i < NH * NC; i += 256) w[i] = Wout[i];
    const int v = blockIdx.x * 4 + wid;   // grid = NV/4 exactly
    xs[wid][lane] = X[v * NH + lane];
    __syncthreads();
    float logit = -INFINITY;
    if (lane < NC) {
        float acc = bout[lane];
#pragma unroll 8
        for (int j = 0; j < NH; ++j) acc += xs[wid][j] * w[j * NC + lane];
        logit = acc;
    }
    float m = logit;
#pragma unroll
    for (int o = 32; o; o >>= 1) { float t = __shfl_xor(m, o); m = t > m ? t : m; }
    float e = lane < NC ? expf(logit - m) : 0.f;
    float s = e;
#pragma unroll
    for (int o = 32; o; o >>= 1) s += __shfl_xor(s, o);
    if (lane < NC) out[v * NC + lane] = logit - m - logf(s);
}

extern "C" void kernel_launch(void* const* d_in, const int* in_sizes, int n_in,
                              void* d_out, int out_size, void* d_ws, size_t ws_size,
                              hipStream_t stream) {
    const float* x    = (const float*)d_in[0];
    const float* degE = (const float*)d_in[1];
    const float* degV = (const float*)d_in[2];
    const float* W0   = (const float*)d_in[3];
    const float* b0   = (const float*)d_in[4];
    const float* Ws   = (const float*)d_in[5];
    const float* Wout = (const float*)d_in[6];
    const float* bout = (const float*)d_in[7];
    const int* vertex = (const int*)d_in[8];
    const int* edges  = (const int*)d_in[9];
    float* out = (float*)d_out;

    float* ws = (float*)d_ws;
    float* X      = ws;                          // NV*NH   = 6.4M floats
    float* X0     = X  + (size_t)NV * NH;        // 6.4M
    float* Xv     = X0 + (size_t)NV * NH;        // 6.4M
    float* Xe     = Xv + (size_t)NV * NH;        // NE*NH   = 1.28M
    float* scaleE = Xe + (size_t)NEg * NH;       // NE      = 20k (counts, then scale)

    // per-edge mean scale: degE/max(count,1)
    hipMemsetAsync(scaleE, 0, NEg * sizeof(float), stream);
    count_kernel<<<(NNZp + 255) / 256, 256, 0, stream>>>(edges, scaleE);
    scale_kernel<<<(NEg + 255) / 256, 256, 0, stream>>>(degE, scaleE);

    // X = relu(x @ W0 + b0); X0 = X
    gemm0_kernel<<<NV / 4, 256, 0, stream>>>(x, W0, b0, X, X0);

    const float betas[4] = {logf(0.5f / 1.f + 1.f), logf(0.5f / 2.f + 1.f),
                            logf(0.5f / 3.f + 1.f), logf(0.5f / 4.f + 1.f)};
    const int scatter_blocks = (NNZp * 64) / 256;   // 400000

    for (int i = 0; i < 4; ++i) {
        hipMemsetAsync(Xe, 0, (size_t)NEg * NH * sizeof(float), stream);
        scatter_ve<<<scatter_blocks, 256, 0, stream>>>(vertex, edges, X, Xe);
        xe_scale<<<(NEg * NH) / 256, 256, 0, stream>>>(Xe, scaleE);
        hipMemsetAsync(Xv, 0, (size_t)NV * NH * sizeof(float), stream);
        scatter_ev<<<scatter_blocks, 256, 0, stream>>>(vertex, edges, Xe, Xv);
        vertex_update<<<NV / 4, 256, 0, stream>>>(Xv, degV, X0,
                                                  Ws + (size_t)i * NH * NH, X, betas[i]);
    }

    output_kernel<<<NV / 4, 256, 0, stream>>>(X, Wout, bout, out);
}

// Round 2
// 1467.169 us; speedup vs baseline: 2.3206x; 2.3206x over previous
//
#include <hip/hip_runtime.h>
#include <math.h>

constexpr int NV   = 100000;
constexpr int NEg  = 20000;
constexpr int NNZp = 1600000;
constexpr int NF   = 128;
constexpr int NH   = 64;
constexpr int NC   = 40;

// ---------------- histogram: cnt_e[e]++, cnt_v[v]++ per incidence ----------------
__global__ __launch_bounds__(256) void hist_kernel(const int* __restrict__ vertex,
                                                   const int* __restrict__ edges,
                                                   int* __restrict__ cnt_e,
                                                   int* __restrict__ cnt_v) {
    int k = blockIdx.x * 256 + threadIdx.x;
    if (k < NNZp) {
        atomicAdd(&cnt_e[edges[k]], 1);
        atomicAdd(&cnt_v[vertex[k]], 1);
    }
}

// scaleE[e] = degE[e] / max(cnt_e[e],1)
__global__ __launch_bounds__(256) void scale_kernel(const float* __restrict__ degE,
                                                    const int* __restrict__ cnt_e,
                                                    float* __restrict__ scaleE) {
    int e = blockIdx.x * 256 + threadIdx.x;
    if (e < NEg) {
        int c = cnt_e[e];
        scaleE[e] = degE[e] / (float)(c < 1 ? 1 : c);
    }
}

// ---------------- single-block exclusive scan: rs[0..n], rs[n] = total ----------------
__global__ __launch_bounds__(1024) void scan_kernel(const int* __restrict__ cnt,
                                                    int* __restrict__ rs, int n) {
    __shared__ int sums[1024];
    const int t = threadIdx.x;
    const int chunk = (n + 1023) >> 10;
    const int b = t * chunk;
    const int e = min(b + chunk, n);
    int s = 0;
    for (int i = b; i < e; ++i) s += cnt[i];
    sums[t] = s;
    __syncthreads();
    for (int off = 1; off < 1024; off <<= 1) {
        int v = (t >= off) ? sums[t - off] : 0;
        __syncthreads();
        sums[t] += v;
        __syncthreads();
    }
    int run = sums[t] - s;   // exclusive base for this chunk
    for (int i = b; i < e; ++i) { rs[i] = run; run += cnt[i]; }
    if (t == 1023) rs[n] = sums[1023];
}

// ---------------- fill sorted incidence lists (consumes cnt_* as cursors) -------
__global__ __launch_bounds__(256) void fill_kernel(const int* __restrict__ vertex,
                                                   const int* __restrict__ edges,
                                                   const int* __restrict__ rs_e,
                                                   const int* __restrict__ rs_v,
                                                   int* __restrict__ cnt_e,
                                                   int* __restrict__ cnt_v,
                                                   int* __restrict__ vid_sorted,
                                                   int* __restrict__ eid_sorted) {
    int k = blockIdx.x * 256 + threadIdx.x;
    if (k < NNZp) {
        int v = vertex[k];
        int e = edges[k];
        int se = rs_e[e] + atomicSub(&cnt_e[e], 1) - 1;
        vid_sorted[se] = v;
        int sv = rs_v[v] + atomicSub(&cnt_v[v], 1) - 1;
        eid_sorted[sv] = e;
    }
}

// ---------------- X = relu(x @ W0 + b0); X0 = X ----------------
__global__ __launch_bounds__(256) void gemm0_kernel(const float* __restrict__ x,
                                                    const float* __restrict__ W0,
                                                    const float* __restrict__ b0,
                                                    float* __restrict__ X,
                                                    float* __restrict__ X0) {
    __shared__ float w[NF * NH];
    __shared__ float xs[4][NF];
    const int lane = threadIdx.x & 63;
    const int wid  = threadIdx.x >> 6;
    for (int i = threadIdx.x; i < NF * NH; i += 256) w[i] = W0[i];
    const int row = blockIdx.x * 4 + wid;   // grid = NV/4 exactly
    xs[wid][lane]      = x[row * NF + lane];
    xs[wid][lane + 64] = x[row * NF + 64 + lane];
    __syncthreads();
    float acc = b0[lane];
#pragma unroll 8
    for (int j = 0; j < NF; ++j) acc += xs[wid][j] * w[j * NH + lane];
    float r = acc > 0.f ? acc : 0.f;
    X[row * NH + lane]  = r;
    X0[row * NH + lane] = r;
}

// ---------------- vertex -> edge GATHER: Xe[e] = scaleE[e] * sum_{v in e} X[v] ---
// one wave per edge, lane = feature, 4-wide index prefetch
__global__ __launch_bounds__(256) void gather_ve(const int* __restrict__ rs_e,
                                                 const int* __restrict__ vid_sorted,
                                                 const float* __restrict__ X,
                                                 const float* __restrict__ scaleE,
                                                 float* __restrict__ Xe) {
    const int lane = threadIdx.x & 63;
    const int e = blockIdx.x * 4 + (threadIdx.x >> 6);   // grid = NE/4 exactly
    const int b  = rs_e[e];
    const int en = rs_e[e + 1];
    float acc = 0.f;
    int m = b;
    for (; m + 4 <= en; m += 4) {
        int i0 = vid_sorted[m];
        int i1 = vid_sorted[m + 1];
        int i2 = vid_sorted[m + 2];
        int i3 = vid_sorted[m + 3];
        acc += X[(size_t)i0 * NH + lane];
        acc += X[(size_t)i1 * NH + lane];
        acc += X[(size_t)i2 * NH + lane];
        acc += X[(size_t)i3 * NH + lane];
    }
    for (; m < en; ++m) acc += X[(size_t)vid_sorted[m] * NH + lane];
    Xe[(size_t)e * NH + lane] = acc * scaleE[e];
}

// ---------------- edge -> vertex GATHER fused with vertex update -----------------
// Xv[v] = degV[v] * sum_{e ni v} Xe[e]; normalize; residual; 64x64 GEMM; relu
__global__ __launch_bounds__(256) void gather_ev_update(const int* __restrict__ rs_v,
                                                        const int* __restrict__ eid_sorted,
                                                        const float* __restrict__ Xe,
                                                        const float* __restrict__ degV,
                                                        const float* __restrict__ X0,
                                                        const float* __restrict__ Wl,
                                                        float* __restrict__ X,
                                                        float beta) {
    __shared__ float w[NH * NH];     // 16 KB
    __shared__ float xis[4][NH];
    const int lane = threadIdx.x & 63;
    const int wid  = threadIdx.x >> 6;
    for (int i = threadIdx.x; i < NH * NH; i += 256) w[i] = Wl[i];
    const int v = blockIdx.x * 4 + wid;   // grid = NV/4 exactly
    const int b  = rs_v[v];
    const int en = rs_v[v + 1];
    float acc = 0.f;
    int m = b;
    for (; m + 4 <= en; m += 4) {
        int i0 = eid_sorted[m];
        int i1 = eid_sorted[m + 1];
        int i2 = eid_sorted[m + 2];
        int i3 = eid_sorted[m + 3];
        acc += Xe[(size_t)i0 * NH + lane];
        acc += Xe[(size_t)i1 * NH + lane];
        acc += Xe[(size_t)i2 * NH + lane];
        acc += Xe[(size_t)i3 * NH + lane];
    }
    for (; m < en; ++m) acc += Xe[(size_t)eid_sorted[m] * NH + lane];

    float xv = acc * degV[v];
    float sq = xv * xv;
#pragma unroll
    for (int o = 32; o; o >>= 1) sq += __shfl_xor(sq, o);
    float norm = sqrtf(sq);
    float xn = norm > 0.f ? xv / norm : 0.f;
    float xi = 0.9f * xn + 0.1f * X0[(size_t)v * NH + lane];
    xis[wid][lane] = xi;
    __syncthreads();
    float gacc = 0.f;
#pragma unroll 8
    for (int j = 0; j < NH; ++j) gacc += xis[wid][j] * w[j * NH + lane];
    float outv = (1.f - beta) * xi + beta * gacc;
    X[(size_t)v * NH + lane] = outv > 0.f ? outv : 0.f;
}

// ---------------- logits = X @ Wout + bout ; log_softmax ----------------
__global__ __launch_bounds__(256) void output_kernel(const float* __restrict__ X,
                                                     const float* __restrict__ Wout,
                                                     const float* __restrict__ bout,
                                                     float* __restrict__ out) {
    __shared__ float w[NH * NC];     // 10.24 KB
    __shared__ float xs[4][NH];
    const int lane = threadIdx.x & 63;
    const int wid  = threadIdx.x >> 6;
    for (int i = threadIdx.x; i < NH * NC; i += 256) w[i] = Wout[i];
    const int v = blockIdx.x * 4 + wid;   // grid = NV/4 exactly
    xs[wid][lane] = X[(size_t)v * NH + lane];
    __syncthreads();
    float logit = -INFINITY;
    if (lane < NC) {
        float acc = bout[lane];
#pragma unroll 8
        for (int j = 0; j < NH; ++j) acc += xs[wid][j] * w[j * NC + lane];
        logit = acc;
    }
    float m = logit;
#pragma unroll
    for (int o = 32; o; o >>= 1) { float t = __shfl_xor(m, o); m = t > m ? t : m; }
    float e = lane < NC ? expf(logit - m) : 0.f;
    float s = e;
#pragma unroll
    for (int o = 32; o; o >>= 1) s += __shfl_xor(s, o);
    if (lane < NC) out[(size_t)v * NC + lane] = logit - m - logf(s);
}

extern "C" void kernel_launch(void* const* d_in, const int* in_sizes, int n_in,
                              void* d_out, int out_size, void* d_ws, size_t ws_size,
                              hipStream_t stream) {
    const float* x    = (const float*)d_in[0];
    const float* degE = (const float*)d_in[1];
    const float* degV = (const float*)d_in[2];
    const float* W0   = (const float*)d_in[3];
    const float* b0   = (const float*)d_in[4];
    const float* Ws   = (const float*)d_in[5];
    const float* Wout = (const float*)d_in[6];
    const float* bout = (const float*)d_in[7];
    const int* vertex = (const int*)d_in[8];
    const int* edges  = (const int*)d_in[9];
    float* out = (float*)d_out;

    // workspace layout (all 4-byte elems): ~70 MB total
    float* ws = (float*)d_ws;
    float* X      = ws;                            // NV*NH   = 6.4M
    float* X0     = X  + (size_t)NV * NH;          // 6.4M
    float* Xe     = X0 + (size_t)NV * NH;          // NE*NH   = 1.28M
    float* scaleE = Xe + (size_t)NEg * NH;         // 20k
    int* cnt_e      = (int*)(scaleE + NEg);        // 20k
    int* cnt_v      = cnt_e + NEg;                 // 100k
    int* rs_e       = cnt_v + NV;                  // 20k+1
    int* rs_v       = rs_e + (NEg + 1);            // 100k+1
    int* vid_sorted = rs_v + (NV + 1);             // 1.6M
    int* eid_sorted = vid_sorted + NNZp;           // 1.6M

    // ---- CSR build (per call; ws is re-poisoned before every timed launch) ----
    hipMemsetAsync(cnt_e, 0, NEg * sizeof(int), stream);
    hipMemsetAsync(cnt_v, 0, NV * sizeof(int), stream);
    hist_kernel<<<(NNZp + 255) / 256, 256, 0, stream>>>(vertex, edges, cnt_e, cnt_v);
    scale_kernel<<<(NEg + 255) / 256, 256, 0, stream>>>(degE, cnt_e, scaleE);
    scan_kernel<<<1, 1024, 0, stream>>>(cnt_e, rs_e, NEg);
    scan_kernel<<<1, 1024, 0, stream>>>(cnt_v, rs_v, NV);
    fill_kernel<<<(NNZp + 255) / 256, 256, 0, stream>>>(vertex, edges, rs_e, rs_v,
                                                        cnt_e, cnt_v, vid_sorted, eid_sorted);

    // ---- X = relu(x @ W0 + b0); X0 = X ----
    gemm0_kernel<<<NV / 4, 256, 0, stream>>>(x, W0, b0, X, X0);

    const float betas[4] = {logf(0.5f / 1.f + 1.f), logf(0.5f / 2.f + 1.f),
                            logf(0.5f / 3.f + 1.f), logf(0.5f / 4.f + 1.f)};

    for (int i = 0; i < 4; ++i) {
        gather_ve<<<NEg / 4, 256, 0, stream>>>(rs_e, vid_sorted, X, scaleE, Xe);
        gather_ev_update<<<NV / 4, 256, 0, stream>>>(rs_v, eid_sorted, Xe, degV, X0,
                                                     Ws + (size_t)i * NH * NH, X, betas[i]);
    }

    output_kernel<<<NV / 4, 256, 0, stream>>>(X, Wout, bout, out);
}

// Round 3
// 1073.178 us; speedup vs baseline: 3.1726x; 1.3671x over previous
//
#include <hip/hip_runtime.h>
#include <math.h>

constexpr int NV   = 100000;
constexpr int NEg  = 20000;
constexpr int NNZp = 1600000;
constexpr int NF   = 128;
constexpr int NH   = 64;
constexpr int NC   = 40;

constexpr int NBUCK_E = (NEg + 63) / 64;   // 313
constexpr int NBUCK_V = (NV  + 63) / 64;   // 1563
constexpr int CAP_E = 8192;                // avg bucket 5120, sd ~72
constexpr int CAP_V = 2048;                // avg bucket 1024, sd ~32

// ---------------- histogram: cnt_e[e]++, cnt_v[v]++ ----------------
__global__ __launch_bounds__(256) void hist_kernel(const int* __restrict__ vertex,
                                                   const int* __restrict__ edges,
                                                   int* __restrict__ cnt_e,
                                                   int* __restrict__ cnt_v) {
    int k = blockIdx.x * 256 + threadIdx.x;   // grid = NNZ/256 exact
    atomicAdd(&cnt_e[edges[k]], 1);
    atomicAdd(&cnt_v[vertex[k]], 1);
}

// scaleE[e] = degE[e] / max(cnt_e[e],1)
__global__ __launch_bounds__(256) void scale_kernel(const float* __restrict__ degE,
                                                    const int* __restrict__ cnt_e,
                                                    float* __restrict__ scaleE) {
    int e = blockIdx.x * 256 + threadIdx.x;
    if (e < NEg) {
        int c = cnt_e[e];
        scaleE[e] = degE[e] / (float)(c < 1 ? 1 : c);
    }
}

// ---------------- multi-block exclusive scan (O(n^2/1024) prefix re-sum) -------
__global__ __launch_bounds__(256) void scan_kernel2(const int* __restrict__ cnt,
                                                    int* __restrict__ rs, int n) {
    __shared__ int red[256];
    __shared__ int wsum[4];
    const int tid = threadIdx.x;
    const int g = blockIdx.x;
    const int blockBase = g << 10;
    int pre = 0;
    for (int i = tid; i < blockBase; i += 256) pre += cnt[i];
    red[tid] = pre;
    __syncthreads();
    for (int s = 128; s > 0; s >>= 1) {
        if (tid < s) red[tid] += red[tid + s];
        __syncthreads();
    }
    const int base0 = red[0];
    const int i0 = blockBase + tid * 4;
    int v0 = (i0 + 0 < n) ? cnt[i0 + 0] : 0;
    int v1 = (i0 + 1 < n) ? cnt[i0 + 1] : 0;
    int v2 = (i0 + 2 < n) ? cnt[i0 + 2] : 0;
    int v3 = (i0 + 3 < n) ? cnt[i0 + 3] : 0;
    int tsum = v0 + v1 + v2 + v3;
    const int lane = tid & 63, wv = tid >> 6;
    int incl = tsum;
    for (int o = 1; o < 64; o <<= 1) {
        int u = __shfl_up(incl, o);
        if (lane >= o) incl += u;
    }
    if (lane == 63) wsum[wv] = incl;
    __syncthreads();
    int wbase = 0;
    for (int q = 0; q < wv; ++q) wbase += wsum[q];
    int excl = base0 + wbase + (incl - tsum);
    if (i0 + 0 < n) rs[i0 + 0] = excl;
    if (i0 + 1 < n) rs[i0 + 1] = excl + v0;
    if (i0 + 2 < n) rs[i0 + 2] = excl + v0 + v1;
    if (i0 + 3 < n) rs[i0 + 3] = excl + v0 + v1 + v2;
    if (g == gridDim.x - 1 && tid == 255) rs[n] = excl + tsum;
}

// ---------------- phase 2: partition packed words into coarse buckets ----------
// cursors padded to 64B (16 ints) to avoid same-line atomic serialization
__global__ __launch_bounds__(256) void partition_kernel(const int* __restrict__ vertex,
                                                        const int* __restrict__ edges,
                                                        const int* __restrict__ rs_e,
                                                        const int* __restrict__ rs_v,
                                                        int* __restrict__ cur_e,
                                                        int* __restrict__ cur_v,
                                                        int* __restrict__ vid_sorted,
                                                        int* __restrict__ eid_sorted) {
    int k = blockIdx.x * 256 + threadIdx.x;   // grid = NNZ/256 exact
    int v = vertex[k];
    int e = edges[k];
    int be = e >> 6;
    int pe = atomicAdd(&cur_e[be * 16], 1);
    vid_sorted[rs_e[be << 6] + pe] = (v << 6) | (e & 63);
    int bv = v >> 6;
    int pv = atomicAdd(&cur_v[bv * 16], 1);
    eid_sorted[rs_v[bv << 6] + pv] = (e << 6) | (v & 63);
}

// ---------------- phase 3: per-bucket LDS counting sort, in place --------------
template <int CAP>
__global__ __launch_bounds__(256) void local_sort(const int* __restrict__ rs,
                                                  int* __restrict__ buf, int n_ids) {
    __shared__ int lds_out[CAP];
    __shared__ int hist[64], off[64], cnt2[64];
    const int b = blockIdx.x;
    const int i0 = b << 6;
    const int base = rs[i0];
    const int iend = min(i0 + 64, n_ids);
    const int sz = rs[iend] - base;
    const int tid = threadIdx.x;
    if (tid < 64) { hist[tid] = 0; cnt2[tid] = 0; }
    __syncthreads();
    for (int t = tid; t < sz; t += 256) atomicAdd(&hist[buf[base + t] & 63], 1);
    __syncthreads();
    if (tid < 64) {
        int h = hist[tid];
        int incl = h;
        for (int o = 1; o < 64; o <<= 1) {
            int u = __shfl_up(incl, o);
            if (tid >= o) incl += u;
        }
        off[tid] = incl - h;
    }
    __syncthreads();
    for (int t = tid; t < sz; t += 256) {
        int w = buf[base + t];
        int f = w & 63;
        int rk = off[f] + atomicAdd(&cnt2[f], 1);
        lds_out[rk] = w >> 6;
    }
    __syncthreads();
    for (int t = tid; t < sz; t += 256) buf[base + t] = lds_out[t];
}

// ---------------- X = relu(x @ W0 + b0); X0 = X  (quarter-wave per row) --------
__global__ __launch_bounds__(256) void gemm0_kernel(const float* __restrict__ x,
                                                    const float* __restrict__ W0,
                                                    const float* __restrict__ b0,
                                                    float* __restrict__ X,
                                                    float* __restrict__ X0) {
    __shared__ float w[NF * NH];   // 32 KB
    __shared__ float xr[16][NF];   // 8 KB
    const int tid = threadIdx.x;
    const int l16 = tid & 15;
    const int r   = tid >> 4;                 // 0..15 row slot
    for (int i = tid; i < NF * NH; i += 256) w[i] = W0[i];
    const int row = blockIdx.x * 16 + r;      // grid = NV/16 exact
    float4 a0 = *((const float4*)(x + (size_t)row * NF) + l16);
    float4 a1 = *((const float4*)(x + (size_t)row * NF + 64) + l16);
    *((float4*)&xr[r][0] + l16)  = a0;
    *((float4*)&xr[r][64] + l16) = a1;
    __syncthreads();
    float4 acc = *((const float4*)b0 + l16);
#pragma unroll 8
    for (int j = 0; j < NF; ++j) {
        float xj = xr[r][j];
        float4 wv = *((const float4*)&w[j * NH] + l16);
        acc.x += xj * wv.x; acc.y += xj * wv.y;
        acc.z += xj * wv.z; acc.w += xj * wv.w;
    }
    acc.x = acc.x > 0.f ? acc.x : 0.f;
    acc.y = acc.y > 0.f ? acc.y : 0.f;
    acc.z = acc.z > 0.f ? acc.z : 0.f;
    acc.w = acc.w > 0.f ? acc.w : 0.f;
    *((float4*)(X  + (size_t)row * NH) + l16) = acc;
    *((float4*)(X0 + (size_t)row * NH) + l16) = acc;
}

// ---------------- v->e gather: Xe[e] = scaleE[e] * sum X[v]  (quarter per edge) -
__global__ __launch_bounds__(256) void gather_ve(const int* __restrict__ rs_e,
                                                 const int* __restrict__ vid_sorted,
                                                 const float* __restrict__ X,
                                                 const float* __restrict__ scaleE,
                                                 float* __restrict__ Xe) {
    const int tid = threadIdx.x;
    const int l16 = tid & 15;
    const int e = blockIdx.x * 16 + (tid >> 4);   // grid = NE/16 exact
    const int b  = rs_e[e];
    const int en = rs_e[e + 1];
    float4 acc = {0.f, 0.f, 0.f, 0.f};
    int m = b;
    for (; m + 2 <= en; m += 2) {
        int i0 = vid_sorted[m];
        int i1 = vid_sorted[m + 1];
        float4 p = *((const float4*)(X + (size_t)i0 * NH) + l16);
        float4 q = *((const float4*)(X + (size_t)i1 * NH) + l16);
        acc.x += p.x + q.x; acc.y += p.y + q.y;
        acc.z += p.z + q.z; acc.w += p.w + q.w;
    }
    if (m < en) {
        int i0 = vid_sorted[m];
        float4 p = *((const float4*)(X + (size_t)i0 * NH) + l16);
        acc.x += p.x; acc.y += p.y; acc.z += p.z; acc.w += p.w;
    }
    float s = scaleE[e];
    acc.x *= s; acc.y *= s; acc.z *= s; acc.w *= s;
    *((float4*)(Xe + (size_t)e * NH) + l16) = acc;
}

// ---------------- e->v gather fused with normalize/residual/GEMM/relu ----------
__global__ __launch_bounds__(256) void gather_ev_update(const int* __restrict__ rs_v,
                                                        const int* __restrict__ eid_sorted,
                                                        const float* __restrict__ Xe,
                                                        const float* __restrict__ degV,
                                                        const float* __restrict__ X0,
                                                        const float* __restrict__ Wl,
                                                        float* __restrict__ X,
                                                        float beta) {
    __shared__ float w[NH * NH];   // 16 KB
    __shared__ float xis[16][NH];  // 4 KB
    const int tid = threadIdx.x;
    const int l16 = tid & 15;
    const int r   = tid >> 4;
    for (int i = tid; i < NH * NH; i += 256) w[i] = Wl[i];
    const int v = blockIdx.x * 16 + r;        // grid = NV/16 exact
    const int b  = rs_v[v];
    const int en = rs_v[v + 1];
    float4 acc = {0.f, 0.f, 0.f, 0.f};
    int m = b;
    for (; m + 2 <= en; m += 2) {
        int i0 = eid_sorted[m];
        int i1 = eid_sorted[m + 1];
        float4 p = *((const float4*)(Xe + (size_t)i0 * NH) + l16);
        float4 q = *((const float4*)(Xe + (size_t)i1 * NH) + l16);
        acc.x += p.x + q.x; acc.y += p.y + q.y;
        acc.z += p.z + q.z; acc.w += p.w + q.w;
    }
    if (m < en) {
        int i0 = eid_sorted[m];
        float4 p = *((const float4*)(Xe + (size_t)i0 * NH) + l16);
        acc.x += p.x; acc.y += p.y; acc.z += p.z; acc.w += p.w;
    }
    float dv = degV[v];
    acc.x *= dv; acc.y *= dv; acc.z *= dv; acc.w *= dv;
    float sq = acc.x * acc.x + acc.y * acc.y + acc.z * acc.z + acc.w * acc.w;
#pragma unroll
    for (int o = 1; o < 16; o <<= 1) sq += __shfl_xor(sq, o);
    float norm = sqrtf(sq);
    float inv = norm > 0.f ? 1.f / norm : 0.f;
    float4 x04 = *((const float4*)(X0 + (size_t)v * NH) + l16);
    float4 xi;
    xi.x = 0.9f * acc.x * inv + 0.1f * x04.x;
    xi.y = 0.9f * acc.y * inv + 0.1f * x04.y;
    xi.z = 0.9f * acc.z * inv + 0.1f * x04.z;
    xi.w = 0.9f * acc.w * inv + 0.1f * x04.w;
    *((float4*)&xis[r][0] + l16) = xi;
    __syncthreads();
    float4 g = {0.f, 0.f, 0.f, 0.f};
#pragma unroll 8
    for (int j = 0; j < NH; ++j) {
        float xj = xis[r][j];
        float4 wv = *((const float4*)&w[j * NH] + l16);
        g.x += xj * wv.x; g.y += xj * wv.y;
        g.z += xj * wv.z; g.w += xj * wv.w;
    }
    float ob = 1.f - beta;
    float4 o4;
    o4.x = ob * xi.x + beta * g.x;
    o4.y = ob * xi.y + beta * g.y;
    o4.z = ob * xi.z + beta * g.z;
    o4.w = ob * xi.w + beta * g.w;
    o4.x = o4.x > 0.f ? o4.x : 0.f;
    o4.y = o4.y > 0.f ? o4.y : 0.f;
    o4.z = o4.z > 0.f ? o4.z : 0.f;
    o4.w = o4.w > 0.f ? o4.w : 0.f;
    *((float4*)(X + (size_t)v * NH) + l16) = o4;
}

// ---------------- logits = X @ Wout + bout ; log_softmax ----------------
__global__ __launch_bounds__(256) void output_kernel(const float* __restrict__ X,
                                                     const float* __restrict__ Wout,
                                                     const float* __restrict__ bout,
                                                     float* __restrict__ out) {
    __shared__ float w[NH * NC];
    __shared__ float xs[4][NH];
    const int lane = threadIdx.x & 63;
    const int wid  = threadIdx.x >> 6;
    for (int i = threadIdx.x; i < NH * NC; i += 256) w[i] = Wout[i];
    const int v = blockIdx.x * 4 + wid;   // grid = NV/4 exact
    xs[wid][lane] = X[(size_t)v * NH + lane];
    __syncthreads();
    float logit = -INFINITY;
    if (lane < NC) {
        float acc = bout[lane];
#pragma unroll 8
        for (int j = 0; j < NH; ++j) acc += xs[wid][j] * w[j * NC + lane];
        logit = acc;
    }
    float m = logit;
#pragma unroll
    for (int o = 32; o; o >>= 1) { float t = __shfl_xor(m, o); m = t > m ? t : m; }
    float e = lane < NC ? expf(logit - m) : 0.f;
    float s = e;
#pragma unroll
    for (int o = 32; o; o >>= 1) s += __shfl_xor(s, o);
    if (lane < NC) out[(size_t)v * NC + lane] = logit - m - logf(s);
}

extern "C" void kernel_launch(void* const* d_in, const int* in_sizes, int n_in,
                              void* d_out, int out_size, void* d_ws, size_t ws_size,
                              hipStream_t stream) {
    const float* x    = (const float*)d_in[0];
    const float* degE = (const float*)d_in[1];
    const float* degV = (const float*)d_in[2];
    const float* W0   = (const float*)d_in[3];
    const float* b0   = (const float*)d_in[4];
    const float* Ws   = (const float*)d_in[5];
    const float* Wout = (const float*)d_in[6];
    const float* bout = (const float*)d_in[7];
    const int* vertex = (const int*)d_in[8];
    const int* edges  = (const int*)d_in[9];
    float* out = (float*)d_out;

    // workspace layout (~70.5 MB)
    float* ws = (float*)d_ws;
    float* X      = ws;                            // 6.4M
    float* X0     = X  + (size_t)NV * NH;          // 6.4M
    float* Xe     = X0 + (size_t)NV * NH;          // 1.28M
    float* scaleE = Xe + (size_t)NEg * NH;         // 20k
    int* cnt_e      = (int*)(scaleE + NEg);        // 20k
    int* cnt_v      = cnt_e + NEg;                 // 100k
    int* rs_e       = cnt_v + NV;                  // 20k+1
    int* rs_v       = rs_e + (NEg + 4);            // 100k+1 (padded start)
    int* cur_e      = rs_v + (NV + 4);             // 313*16
    int* cur_v      = cur_e + NBUCK_E * 16;        // 1563*16
    int* vid_sorted = cur_v + NBUCK_V * 16;        // 1.6M
    int* eid_sorted = vid_sorted + NNZp;           // 1.6M

    // ---- CSR build ----
    hipMemsetAsync(cnt_e, 0, NEg * sizeof(int), stream);
    hipMemsetAsync(cnt_v, 0, NV * sizeof(int), stream);
    hipMemsetAsync(cur_e, 0, NBUCK_E * 16 * sizeof(int), stream);
    hipMemsetAsync(cur_v, 0, NBUCK_V * 16 * sizeof(int), stream);
    hist_kernel<<<NNZp / 256, 256, 0, stream>>>(vertex, edges, cnt_e, cnt_v);
    scale_kernel<<<(NEg + 255) / 256, 256, 0, stream>>>(degE, cnt_e, scaleE);
    scan_kernel2<<<(NEg + 1023) / 1024, 256, 0, stream>>>(cnt_e, rs_e, NEg);
    scan_kernel2<<<(NV + 1023) / 1024, 256, 0, stream>>>(cnt_v, rs_v, NV);
    partition_kernel<<<NNZp / 256, 256, 0, stream>>>(vertex, edges, rs_e, rs_v,
                                                     cur_e, cur_v, vid_sorted, eid_sorted);
    local_sort<CAP_E><<<NBUCK_E, 256, 0, stream>>>(rs_e, vid_sorted, NEg);
    local_sort<CAP_V><<<NBUCK_V, 256, 0, stream>>>(rs_v, eid_sorted, NV);

    // ---- X = relu(x @ W0 + b0); X0 = X ----
    gemm0_kernel<<<NV / 16, 256, 0, stream>>>(x, W0, b0, X, X0);

    const float betas[4] = {logf(0.5f / 1.f + 1.f), logf(0.5f / 2.f + 1.f),
                            logf(0.5f / 3.f + 1.f), logf(0.5f / 4.f + 1.f)};

    for (int i = 0; i < 4; ++i) {
        gather_ve<<<NEg / 16, 256, 0, stream>>>(rs_e, vid_sorted, X, scaleE, Xe);
        gather_ev_update<<<NV / 16, 256, 0, stream>>>(rs_v, eid_sorted, Xe, degV, X0,
                                                      Ws + (size_t)i * NH * NH, X, betas[i]);
    }

    output_kernel<<<NV / 4, 256, 0, stream>>>(X, Wout, bout, out);
}

// Round 4
// 783.996 us; speedup vs baseline: 4.3428x; 1.3689x over previous
//
#include <hip/hip_runtime.h>
#include <math.h>

constexpr int NV   = 100000;
constexpr int NEg  = 20000;
constexpr int NNZp = 1600000;
constexpr int NF   = 128;
constexpr int NH   = 64;
constexpr int NC   = 40;

constexpr int WE  = 64;                       // e-bucket width
constexpr int NBE = (NEg + WE - 1) / WE;      // 313
constexpr int WV  = 256;                      // v-bucket width
constexpr int NBV = (NV + WV - 1) / WV;       // 391
constexpr int CAP_E = 6400;                   // e-bucket mean 5120, sd ~71
constexpr int CAP_V = 4864;                   // v-bucket mean 4096, sd ~64
constexpr int CH   = 8192;                    // partition chunk per block
constexpr int PBLK = (NNZp + CH - 1) / CH;    // 196

// ---------------- coarse histograms (bucket granularity only) ----------------
__global__ __launch_bounds__(256) void coarse_hist(const int* __restrict__ vertex,
                                                   const int* __restrict__ edges,
                                                   int* __restrict__ cnt_be,
                                                   int* __restrict__ cnt_bv) {
    __shared__ int he[NBE], hv[NBV];
    for (int i = threadIdx.x; i < NBE; i += 256) he[i] = 0;
    for (int i = threadIdx.x; i < NBV; i += 256) hv[i] = 0;
    __syncthreads();
    const int base = blockIdx.x * 4096;
    const int end  = min(base + 4096, NNZp);
    for (int i = base + threadIdx.x; i < end; i += 256) {
        atomicAdd(&he[edges[i]  >> 6], 1);
        atomicAdd(&hv[vertex[i] >> 8], 1);
    }
    __syncthreads();
    for (int i = threadIdx.x; i < NBE; i += 256) if (he[i]) atomicAdd(&cnt_be[i], he[i]);
    for (int i = threadIdx.x; i < NBV; i += 256) if (hv[i]) atomicAdd(&cnt_bv[i], hv[i]);
}

// ---------------- tiny bucket scans (n<=512), block 0 = e, block 1 = v --------
__global__ __launch_bounds__(512) void scan_buckets(const int* __restrict__ cnt_be,
                                                    const int* __restrict__ cnt_bv,
                                                    int* __restrict__ rsb_e,
                                                    int* __restrict__ rsb_v,
                                                    int* __restrict__ rs_e,
                                                    int* __restrict__ rs_v) {
    __shared__ int s[512];
    const int n      = (blockIdx.x == 0) ? NBE : NBV;
    const int* c     = (blockIdx.x == 0) ? cnt_be : cnt_bv;
    int* r           = (blockIdx.x == 0) ? rsb_e : rsb_v;
    const int t = threadIdx.x;
    int v = (t < n) ? c[t] : 0;
    s[t] = v;
    __syncthreads();
    for (int o = 1; o < 512; o <<= 1) {
        int u = (t >= o) ? s[t - o] : 0;
        __syncthreads();
        s[t] += u;
        __syncthreads();
    }
    if (t < n) r[t] = s[t] - v;          // exclusive
    if (t == 0) {
        r[n] = NNZp;
        if (blockIdx.x == 0) rs_e[NEg] = NNZp;
        else                 rs_v[NV]  = NNZp;
    }
}

// ---------------- partition with per-block run reservation --------------------
// pass1: LDS hist of this block's chunk; one global atomic per (block,bucket);
// pass2: items written into the block's contiguous run -> lines merge in L2.
template <int FB, int NBUCK>
__global__ __launch_bounds__(256) void partition_k(const int* __restrict__ key,
                                                   const int* __restrict__ val,
                                                   const int* __restrict__ rsb,
                                                   int* __restrict__ gcur,
                                                   int* __restrict__ outbuf) {
    __shared__ int cur[NBUCK];
    for (int i = threadIdx.x; i < NBUCK; i += 256) cur[i] = 0;
    __syncthreads();
    const int base = blockIdx.x * CH;
    const int end  = min(base + CH, NNZp);
    for (int i = base + threadIdx.x; i < end; i += 256)
        atomicAdd(&cur[key[i] >> FB], 1);
    __syncthreads();
    for (int i = threadIdx.x; i < NBUCK; i += 256) {
        int h = cur[i];
        cur[i] = rsb[i] + (h ? atomicAdd(&gcur[i], h) : 0);
    }
    __syncthreads();
    for (int i = base + threadIdx.x; i < end; i += 256) {
        int k = key[i];
        int b = k >> FB;
        int pos = atomicAdd(&cur[b], 1);
        outbuf[pos] = (val[i] << FB) | (k & ((1 << FB) - 1));
    }
}

// ---------------- per-bucket LDS counting sort; emits rs (+scaleE) ------------
template <int CAP, int FB, int NID, bool DO_SCALE>
__global__ __launch_bounds__(256) void local_sort_k(const int* __restrict__ rsb,
                                                    int* __restrict__ buf,
                                                    int* __restrict__ rs,
                                                    const float* __restrict__ degE,
                                                    float* __restrict__ scaleE) {
    constexpr int W = 1 << FB;
    __shared__ int stage[CAP];
    __shared__ int hist[W], off[W], cnt2[W];
    const int b = blockIdx.x;
    const int base = rsb[b];
    const int sz   = rsb[b + 1] - base;
    const int tid = threadIdx.x;
    for (int i = tid; i < W; i += 256) { hist[i] = 0; cnt2[i] = 0; }
    __syncthreads();
    for (int t = tid; t < sz; t += 256) atomicAdd(&hist[buf[base + t] & (W - 1)], 1);
    __syncthreads();
    // exclusive scan hist -> off (Hillis-Steele over LDS, W<=256)
    {
        int v = (tid < W) ? hist[tid] : 0;
        if (tid < W) off[tid] = v;
        __syncthreads();
        for (int o = 1; o < W; o <<= 1) {
            int u = (tid < W && tid >= o) ? off[tid - o] : 0;
            __syncthreads();
            if (tid < W) off[tid] += u;
            __syncthreads();
        }
        if (tid < W) off[tid] -= v;
    }
    if (tid < W) {
        int gid = b * W + tid;
        if (gid < NID) {
            rs[gid] = base + off[tid];
            if (DO_SCALE) {
                int c = hist[tid];
                scaleE[gid] = degE[gid] / (float)(c < 1 ? 1 : c);
            }
        }
    }
    __syncthreads();
    for (int t = tid; t < sz; t += 256) {
        int w = buf[base + t];
        int f = w & (W - 1);
        int rk = off[f] + atomicAdd(&cnt2[f], 1);
        stage[rk] = w >> FB;
    }
    __syncthreads();
    for (int t = tid; t < sz; t += 256) buf[base + t] = stage[t];
}

// ---------------- X = relu(x @ W0 + b0); X0 = X  (quarter-wave per row) --------
__global__ __launch_bounds__(256) void gemm0_kernel(const float* __restrict__ x,
                                                    const float* __restrict__ W0,
                                                    const float* __restrict__ b0,
                                                    float* __restrict__ X,
                                                    float* __restrict__ X0) {
    __shared__ float w[NF * NH];
    __shared__ float xr[16][NF];
    const int tid = threadIdx.x;
    const int l16 = tid & 15;
    const int r   = tid >> 4;
    for (int i = tid; i < NF * NH; i += 256) w[i] = W0[i];
    const int row = blockIdx.x * 16 + r;      // grid = NV/16 exact
    float4 a0 = *((const float4*)(x + (size_t)row * NF) + l16);
    float4 a1 = *((const float4*)(x + (size_t)row * NF + 64) + l16);
    *((float4*)&xr[r][0] + l16)  = a0;
    *((float4*)&xr[r][64] + l16) = a1;
    __syncthreads();
    float4 acc = *((const float4*)b0 + l16);
#pragma unroll 8
    for (int j = 0; j < NF; ++j) {
        float xj = xr[r][j];
        float4 wv = *((const float4*)&w[j * NH] + l16);
        acc.x += xj * wv.x; acc.y += xj * wv.y;
        acc.z += xj * wv.z; acc.w += xj * wv.w;
    }
    acc.x = acc.x > 0.f ? acc.x : 0.f;
    acc.y = acc.y > 0.f ? acc.y : 0.f;
    acc.z = acc.z > 0.f ? acc.z : 0.f;
    acc.w = acc.w > 0.f ? acc.w : 0.f;
    *((float4*)(X  + (size_t)row * NH) + l16) = acc;
    *((float4*)(X0 + (size_t)row * NH) + l16) = acc;
}

// ---------------- v->e gather: Xe[e] = scaleE[e] * sum X[v] --------------------
__global__ __launch_bounds__(256) void gather_ve(const int* __restrict__ rs_e,
                                                 const int* __restrict__ vid_sorted,
                                                 const float* __restrict__ X,
                                                 const float* __restrict__ scaleE,
                                                 float* __restrict__ Xe) {
    const int tid = threadIdx.x;
    const int l16 = tid & 15;
    const int e = blockIdx.x * 16 + (tid >> 4);   // grid = NE/16 exact
    const int b  = rs_e[e];
    const int en = rs_e[e + 1];
    float4 acc = {0.f, 0.f, 0.f, 0.f};
    int m = b;
    for (; m + 2 <= en; m += 2) {
        int i0 = vid_sorted[m];
        int i1 = vid_sorted[m + 1];
        float4 p = *((const float4*)(X + (size_t)i0 * NH) + l16);
        float4 q = *((const float4*)(X + (size_t)i1 * NH) + l16);
        acc.x += p.x + q.x; acc.y += p.y + q.y;
        acc.z += p.z + q.z; acc.w += p.w + q.w;
    }
    if (m < en) {
        int i0 = vid_sorted[m];
        float4 p = *((const float4*)(X + (size_t)i0 * NH) + l16);
        acc.x += p.x; acc.y += p.y; acc.z += p.z; acc.w += p.w;
    }
    float s = scaleE[e];
    acc.x *= s; acc.y *= s; acc.z *= s; acc.w *= s;
    *((float4*)(Xe + (size_t)e * NH) + l16) = acc;
}

// ---------------- e->v gather fused with normalize/residual/GEMM/relu ----------
__global__ __launch_bounds__(256) void gather_ev_update(const int* __restrict__ rs_v,
                                                        const int* __restrict__ eid_sorted,
                                                        const float* __restrict__ Xe,
                                                        const float* __restrict__ degV,
                                                        const float* __restrict__ X0,
                                                        const float* __restrict__ Wl,
                                                        float* __restrict__ X,
                                                        float beta) {
    __shared__ float w[NH * NH];
    __shared__ float xis[16][NH];
    const int tid = threadIdx.x;
    const int l16 = tid & 15;
    const int r   = tid >> 4;
    for (int i = tid; i < NH * NH; i += 256) w[i] = Wl[i];
    const int v = blockIdx.x * 16 + r;        // grid = NV/16 exact
    const int b  = rs_v[v];
    const int en = rs_v[v + 1];
    float4 acc = {0.f, 0.f, 0.f, 0.f};
    int m = b;
    for (; m + 2 <= en; m += 2) {
        int i0 = eid_sorted[m];
        int i1 = eid_sorted[m + 1];
        float4 p = *((const float4*)(Xe + (size_t)i0 * NH) + l16);
        float4 q = *((const float4*)(Xe + (size_t)i1 * NH) + l16);
        acc.x += p.x + q.x; acc.y += p.y + q.y;
        acc.z += p.z + q.z; acc.w += p.w + q.w;
    }
    if (m < en) {
        int i0 = eid_sorted[m];
        float4 p = *((const float4*)(Xe + (size_t)i0 * NH) + l16);
        acc.x += p.x; acc.y += p.y; acc.z += p.z; acc.w += p.w;
    }
    float dv = degV[v];
    acc.x *= dv; acc.y *= dv; acc.z *= dv; acc.w *= dv;
    float sq = acc.x * acc.x + acc.y * acc.y + acc.z * acc.z + acc.w * acc.w;
#pragma unroll
    for (int o = 1; o < 16; o <<= 1) sq += __shfl_xor(sq, o);
    float norm = sqrtf(sq);
    float inv = norm > 0.f ? 1.f / norm : 0.f;
    float4 x04 = *((const float4*)(X0 + (size_t)v * NH) + l16);
    float4 xi;
    xi.x = 0.9f * acc.x * inv + 0.1f * x04.x;
    xi.y = 0.9f * acc.y * inv + 0.1f * x04.y;
    xi.z = 0.9f * acc.z * inv + 0.1f * x04.z;
    xi.w = 0.9f * acc.w * inv + 0.1f * x04.w;
    *((float4*)&xis[r][0] + l16) = xi;
    __syncthreads();
    float4 g = {0.f, 0.f, 0.f, 0.f};
#pragma unroll 8
    for (int j = 0; j < NH; ++j) {
        float xj = xis[r][j];
        float4 wv = *((const float4*)&w[j * NH] + l16);
        g.x += xj * wv.x; g.y += xj * wv.y;
        g.z += xj * wv.z; g.w += xj * wv.w;
    }
    float ob = 1.f - beta;
    float4 o4;
    o4.x = ob * xi.x + beta * g.x;
    o4.y = ob * xi.y + beta * g.y;
    o4.z = ob * xi.z + beta * g.z;
    o4.w = ob * xi.w + beta * g.w;
    o4.x = o4.x > 0.f ? o4.x : 0.f;
    o4.y = o4.y > 0.f ? o4.y : 0.f;
    o4.z = o4.z > 0.f ? o4.z : 0.f;
    o4.w = o4.w > 0.f ? o4.w : 0.f;
    *((float4*)(X + (size_t)v * NH) + l16) = o4;
}

// ---------------- logits = X @ Wout + bout ; log_softmax ----------------
__global__ __launch_bounds__(256) void output_kernel(const float* __restrict__ X,
                                                     const float* __restrict__ Wout,
                                                     const float* __restrict__ bout,
                                                     float* __restrict__ out) {
    __shared__ float w[NH * NC];
    __shared__ float xs[4][NH];
    const int lane = threadIdx.x & 63;
    const int wid  = threadIdx.x >> 6;
    for (int i = threadIdx.x; i < NH * NC; i += 256) w[i] = Wout[i];
    const int v = blockIdx.x * 4 + wid;   // grid = NV/4 exact
    xs[wid][lane] = X[(size_t)v * NH + lane];
    __syncthreads();
    float logit = -INFINITY;
    if (lane < NC) {
        float acc = bout[lane];
#pragma unroll 8
        for (int j = 0; j < NH; ++j) acc += xs[wid][j] * w[j * NC + lane];
        logit = acc;
    }
    float m = logit;
#pragma unroll
    for (int o = 32; o; o >>= 1) { float t = __shfl_xor(m, o); m = t > m ? t : m; }
    float e = lane < NC ? expf(logit - m) : 0.f;
    float s = e;
#pragma unroll
    for (int o = 32; o; o >>= 1) s += __shfl_xor(s, o);
    if (lane < NC) out[(size_t)v * NC + lane] = logit - m - logf(s);
}

extern "C" void kernel_launch(void* const* d_in, const int* in_sizes, int n_in,
                              void* d_out, int out_size, void* d_ws, size_t ws_size,
                              hipStream_t stream) {
    const float* x    = (const float*)d_in[0];
    const float* degE = (const float*)d_in[1];
    const float* degV = (const float*)d_in[2];
    const float* W0   = (const float*)d_in[3];
    const float* b0   = (const float*)d_in[4];
    const float* Ws   = (const float*)d_in[5];
    const float* Wout = (const float*)d_in[6];
    const float* bout = (const float*)d_in[7];
    const int* vertex = (const int*)d_in[8];
    const int* edges  = (const int*)d_in[9];
    float* out = (float*)d_out;

    // workspace layout (~70 MB)
    float* ws = (float*)d_ws;
    float* X      = ws;                            // 6.4M
    float* X0     = X  + (size_t)NV * NH;          // 6.4M
    float* Xe     = X0 + (size_t)NV * NH;          // 1.28M
    float* scaleE = Xe + (size_t)NEg * NH;         // 20k
    int* cnt_be = (int*)(scaleE + NEg);            // NBE          } one memset
    int* cnt_bv = cnt_be + NBE;                    // NBV          }
    int* gcur_e = cnt_bv + NBV;                    // NBE          }
    int* gcur_v = gcur_e + NBE;                    // NBV          }
    int* rsb_e  = gcur_v + NBV;                    // NBE+1
    int* rsb_v  = rsb_e + (NBE + 1);               // NBV+1
    int* rs_e   = rsb_v + (NBV + 1);               // NEg+1
    int* rs_v   = rs_e + (NEg + 1);                // NV+1
    int* vid_sorted = rs_v + (NV + 1);             // 1.6M
    int* eid_sorted = vid_sorted + NNZp;           // 1.6M

    // ---- CSR build ----
    hipMemsetAsync(cnt_be, 0, (size_t)(NBE + NBV) * 2 * sizeof(int), stream);
    coarse_hist<<<(NNZp + 4095) / 4096, 256, 0, stream>>>(vertex, edges, cnt_be, cnt_bv);
    scan_buckets<<<2, 512, 0, stream>>>(cnt_be, cnt_bv, rsb_e, rsb_v, rs_e, rs_v);
    partition_k<6, NBE><<<PBLK, 256, 0, stream>>>(edges, vertex, rsb_e, gcur_e, vid_sorted);
    partition_k<8, NBV><<<PBLK, 256, 0, stream>>>(vertex, edges, rsb_v, gcur_v, eid_sorted);
    local_sort_k<CAP_E, 6, NEg, true><<<NBE, 256, 0, stream>>>(rsb_e, vid_sorted, rs_e,
                                                               degE, scaleE);
    local_sort_k<CAP_V, 8, NV, false><<<NBV, 256, 0, stream>>>(rsb_v, eid_sorted, rs_v,
                                                               nullptr, nullptr);

    // ---- X = relu(x @ W0 + b0); X0 = X ----
    gemm0_kernel<<<NV / 16, 256, 0, stream>>>(x, W0, b0, X, X0);

    const float betas[4] = {logf(0.5f / 1.f + 1.f), logf(0.5f / 2.f + 1.f),
                            logf(0.5f / 3.f + 1.f), logf(0.5f / 4.f + 1.f)};

    for (int i = 0; i < 4; ++i) {
        gather_ve<<<NEg / 16, 256, 0, stream>>>(rs_e, vid_sorted, X, scaleE, Xe);
        gather_ev_update<<<NV / 16, 256, 0, stream>>>(rs_v, eid_sorted, Xe, degV, X0,
                                                      Ws + (size_t)i * NH * NH, X, betas[i]);
    }

    output_kernel<<<NV / 4, 256, 0, stream>>>(X, Wout, bout, out);
}

// Round 5
// 615.254 us; speedup vs baseline: 5.5339x; 1.2743x over previous
//
#include <hip/hip_runtime.h>
#include <math.h>

constexpr int NV   = 100000;
constexpr int NEg  = 20000;
constexpr int NNZp = 1600000;
constexpr int NF   = 128;
constexpr int NH   = 64;
constexpr int NC   = 40;

constexpr int WE  = 64;                       // e-bucket width
constexpr int NBE = (NEg + WE - 1) / WE;      // 313
constexpr int WV  = 256;                      // v-bucket width
constexpr int NBV = (NV + WV - 1) / WV;       // 391
constexpr int CAP_E = 6400;
constexpr int CAP_V = 4864;
constexpr int CH   = 8192;
constexpr int PBLK = (NNZp + CH - 1) / CH;    // 196

// ---- bf16 <-> fp32 helpers (RNE) ----
__device__ __forceinline__ float bf2f(unsigned short u) {
    unsigned int x = ((unsigned int)u) << 16;
    return __builtin_bit_cast(float, x);
}
__device__ __forceinline__ unsigned short f2bf(float f) {
    unsigned int x = __builtin_bit_cast(unsigned int, f);
    x += 0x7fffu + ((x >> 16) & 1u);
    return (unsigned short)(x >> 16);
}
__device__ __forceinline__ ushort4 pack4(float a, float b, float c, float d) {
    ushort4 u; u.x = f2bf(a); u.y = f2bf(b); u.z = f2bf(c); u.w = f2bf(d);
    return u;
}

// ---------------- coarse histograms (bucket granularity only) ----------------
__global__ __launch_bounds__(256) void coarse_hist(const int* __restrict__ vertex,
                                                   const int* __restrict__ edges,
                                                   int* __restrict__ cnt_be,
                                                   int* __restrict__ cnt_bv) {
    __shared__ int he[NBE], hv[NBV];
    for (int i = threadIdx.x; i < NBE; i += 256) he[i] = 0;
    for (int i = threadIdx.x; i < NBV; i += 256) hv[i] = 0;
    __syncthreads();
    const int base = blockIdx.x * 4096;
    const int end  = min(base + 4096, NNZp);
    for (int i = base + threadIdx.x; i < end; i += 256) {
        atomicAdd(&he[edges[i]  >> 6], 1);
        atomicAdd(&hv[vertex[i] >> 8], 1);
    }
    __syncthreads();
    for (int i = threadIdx.x; i < NBE; i += 256) if (he[i]) atomicAdd(&cnt_be[i], he[i]);
    for (int i = threadIdx.x; i < NBV; i += 256) if (hv[i]) atomicAdd(&cnt_bv[i], hv[i]);
}

// ---------------- tiny bucket scans ----------------
__global__ __launch_bounds__(512) void scan_buckets(const int* __restrict__ cnt_be,
                                                    const int* __restrict__ cnt_bv,
                                                    int* __restrict__ rsb_e,
                                                    int* __restrict__ rsb_v,
                                                    int* __restrict__ rs_e,
                                                    int* __restrict__ rs_v) {
    __shared__ int s[512];
    const int n      = (blockIdx.x == 0) ? NBE : NBV;
    const int* c     = (blockIdx.x == 0) ? cnt_be : cnt_bv;
    int* r           = (blockIdx.x == 0) ? rsb_e : rsb_v;
    const int t = threadIdx.x;
    int v = (t < n) ? c[t] : 0;
    s[t] = v;
    __syncthreads();
    for (int o = 1; o < 512; o <<= 1) {
        int u = (t >= o) ? s[t - o] : 0;
        __syncthreads();
        s[t] += u;
        __syncthreads();
    }
    if (t < n) r[t] = s[t] - v;
    if (t == 0) {
        r[n] = NNZp;
        if (blockIdx.x == 0) rs_e[NEg] = NNZp;
        else                 rs_v[NV]  = NNZp;
    }
}

// ---------------- partition with per-block run reservation --------------------
template <int FB, int NBUCK>
__global__ __launch_bounds__(256) void partition_k(const int* __restrict__ key,
                                                   const int* __restrict__ val,
                                                   const int* __restrict__ rsb,
                                                   int* __restrict__ gcur,
                                                   int* __restrict__ outbuf) {
    __shared__ int cur[NBUCK];
    for (int i = threadIdx.x; i < NBUCK; i += 256) cur[i] = 0;
    __syncthreads();
    const int base = blockIdx.x * CH;
    const int end  = min(base + CH, NNZp);
    for (int i = base + threadIdx.x; i < end; i += 256)
        atomicAdd(&cur[key[i] >> FB], 1);
    __syncthreads();
    for (int i = threadIdx.x; i < NBUCK; i += 256) {
        int h = cur[i];
        cur[i] = rsb[i] + (h ? atomicAdd(&gcur[i], h) : 0);
    }
    __syncthreads();
    for (int i = base + threadIdx.x; i < end; i += 256) {
        int k = key[i];
        int b = k >> FB;
        int pos = atomicAdd(&cur[b], 1);
        outbuf[pos] = (val[i] << FB) | (k & ((1 << FB) - 1));
    }
}

// ---------------- per-bucket LDS counting sort; emits rs (+scaleE) ------------
template <int CAP, int FB, int NID, bool DO_SCALE>
__global__ __launch_bounds__(256) void local_sort_k(const int* __restrict__ rsb,
                                                    int* __restrict__ buf,
                                                    int* __restrict__ rs,
                                                    const float* __restrict__ degE,
                                                    float* __restrict__ scaleE) {
    constexpr int W = 1 << FB;
    __shared__ int stage[CAP];
    __shared__ int hist[W], off[W], cnt2[W];
    const int b = blockIdx.x;
    const int base = rsb[b];
    const int sz   = rsb[b + 1] - base;
    const int tid = threadIdx.x;
    for (int i = tid; i < W; i += 256) { hist[i] = 0; cnt2[i] = 0; }
    __syncthreads();
    for (int t = tid; t < sz; t += 256) atomicAdd(&hist[buf[base + t] & (W - 1)], 1);
    __syncthreads();
    {
        int v = (tid < W) ? hist[tid] : 0;
        if (tid < W) off[tid] = v;
        __syncthreads();
        for (int o = 1; o < W; o <<= 1) {
            int u = (tid < W && tid >= o) ? off[tid - o] : 0;
            __syncthreads();
            if (tid < W) off[tid] += u;
            __syncthreads();
        }
        if (tid < W) off[tid] -= v;
    }
    if (tid < W) {
        int gid = b * W + tid;
        if (gid < NID) {
            rs[gid] = base + off[tid];
            if (DO_SCALE) {
                int c = hist[tid];
                scaleE[gid] = degE[gid] / (float)(c < 1 ? 1 : c);
            }
        }
    }
    __syncthreads();
    for (int t = tid; t < sz; t += 256) {
        int w = buf[base + t];
        int f = w & (W - 1);
        int rk = off[f] + atomicAdd(&cnt2[f], 1);
        stage[rk] = w >> FB;
    }
    __syncthreads();
    for (int t = tid; t < sz; t += 256) buf[base + t] = stage[t];
}

// ---------------- X = relu(x @ W0 + b0); Xbf = bf16(X); X0 = X (fp32) ---------
__global__ __launch_bounds__(256) void gemm0_kernel(const float* __restrict__ x,
                                                    const float* __restrict__ W0,
                                                    const float* __restrict__ b0,
                                                    unsigned short* __restrict__ Xbf,
                                                    float* __restrict__ X0) {
    __shared__ float w[NF * NH];          // 32 KB
    __shared__ float xr[16][NF + 4];      // padded: r-groups on distinct banks
    const int tid = threadIdx.x;
    const int l16 = tid & 15;
    const int r   = tid >> 4;
    for (int i = tid; i < NF * NH; i += 256) w[i] = W0[i];
    const int row = blockIdx.x * 16 + r;      // grid = NV/16 exact
    float4 a0 = *((const float4*)(x + (size_t)row * NF) + l16);
    float4 a1 = *((const float4*)(x + (size_t)row * NF + 64) + l16);
    *((float4*)&xr[r][0] + l16)  = a0;
    *((float4*)&xr[r][64] + l16) = a1;
    __syncthreads();
    float4 acc = *((const float4*)b0 + l16);
#pragma unroll 8
    for (int j = 0; j < NF; ++j) {
        float xj = xr[r][j];
        float4 wv = *((const float4*)&w[j * NH] + l16);
        acc.x += xj * wv.x; acc.y += xj * wv.y;
        acc.z += xj * wv.z; acc.w += xj * wv.w;
    }
    acc.x = acc.x > 0.f ? acc.x : 0.f;
    acc.y = acc.y > 0.f ? acc.y : 0.f;
    acc.z = acc.z > 0.f ? acc.z : 0.f;
    acc.w = acc.w > 0.f ? acc.w : 0.f;
    *((ushort4*)(Xbf + (size_t)row * NH) + l16) = pack4(acc.x, acc.y, acc.z, acc.w);
    *((float4*)(X0 + (size_t)row * NH) + l16) = acc;
}

// ---------------- v->e gather: Xe[e] = scaleE[e] * sum X[v]  (bf16 rows) -------
__global__ __launch_bounds__(256) void gather_ve(const int* __restrict__ rs_e,
                                                 const int* __restrict__ vid_sorted,
                                                 const unsigned short* __restrict__ Xbf,
                                                 const float* __restrict__ scaleE,
                                                 unsigned short* __restrict__ Xebf) {
    const int tid = threadIdx.x;
    const int l16 = tid & 15;
    const int e = blockIdx.x * 16 + (tid >> 4);   // grid = NE/16 exact
    const int b  = rs_e[e];
    const int en = rs_e[e + 1];
    float ax = 0.f, ay = 0.f, az = 0.f, aw = 0.f;
    int m = b;
    for (; m + 4 <= en; m += 4) {
        int i0 = vid_sorted[m];
        int i1 = vid_sorted[m + 1];
        int i2 = vid_sorted[m + 2];
        int i3 = vid_sorted[m + 3];
        ushort4 p = *((const ushort4*)(Xbf + (size_t)i0 * NH) + l16);
        ushort4 q = *((const ushort4*)(Xbf + (size_t)i1 * NH) + l16);
        ushort4 u = *((const ushort4*)(Xbf + (size_t)i2 * NH) + l16);
        ushort4 t = *((const ushort4*)(Xbf + (size_t)i3 * NH) + l16);
        ax += bf2f(p.x) + bf2f(q.x) + bf2f(u.x) + bf2f(t.x);
        ay += bf2f(p.y) + bf2f(q.y) + bf2f(u.y) + bf2f(t.y);
        az += bf2f(p.z) + bf2f(q.z) + bf2f(u.z) + bf2f(t.z);
        aw += bf2f(p.w) + bf2f(q.w) + bf2f(u.w) + bf2f(t.w);
    }
    for (; m < en; ++m) {
        ushort4 p = *((const ushort4*)(Xbf + (size_t)vid_sorted[m] * NH) + l16);
        ax += bf2f(p.x); ay += bf2f(p.y); az += bf2f(p.z); aw += bf2f(p.w);
    }
    float s = scaleE[e];
    *((ushort4*)(Xebf + (size_t)e * NH) + l16) = pack4(ax * s, ay * s, az * s, aw * s);
}

// ---------------- e->v gather fused with normalize/residual/GEMM/relu ----------
__global__ __launch_bounds__(256) void gather_ev_update(const int* __restrict__ rs_v,
                                                        const int* __restrict__ eid_sorted,
                                                        const unsigned short* __restrict__ Xebf,
                                                        const float* __restrict__ degV,
                                                        const float* __restrict__ X0,
                                                        const float* __restrict__ Wl,
                                                        unsigned short* __restrict__ Xbf,
                                                        float beta) {
    __shared__ float w[NH * NH];         // 16 KB
    __shared__ float xis[16][NH + 4];    // padded: r-groups on distinct banks
    const int tid = threadIdx.x;
    const int l16 = tid & 15;
    const int r   = tid >> 4;
    for (int i = tid; i < NH * NH; i += 256) w[i] = Wl[i];
    const int v = blockIdx.x * 16 + r;        // grid = NV/16 exact
    const int b  = rs_v[v];
    const int en = rs_v[v + 1];
    float ax = 0.f, ay = 0.f, az = 0.f, aw = 0.f;
    int m = b;
    for (; m + 4 <= en; m += 4) {
        int i0 = eid_sorted[m];
        int i1 = eid_sorted[m + 1];
        int i2 = eid_sorted[m + 2];
        int i3 = eid_sorted[m + 3];
        ushort4 p = *((const ushort4*)(Xebf + (size_t)i0 * NH) + l16);
        ushort4 q = *((const ushort4*)(Xebf + (size_t)i1 * NH) + l16);
        ushort4 u = *((const ushort4*)(Xebf + (size_t)i2 * NH) + l16);
        ushort4 t = *((const ushort4*)(Xebf + (size_t)i3 * NH) + l16);
        ax += bf2f(p.x) + bf2f(q.x) + bf2f(u.x) + bf2f(t.x);
        ay += bf2f(p.y) + bf2f(q.y) + bf2f(u.y) + bf2f(t.y);
        az += bf2f(p.z) + bf2f(q.z) + bf2f(u.z) + bf2f(t.z);
        aw += bf2f(p.w) + bf2f(q.w) + bf2f(u.w) + bf2f(t.w);
    }
    for (; m < en; ++m) {
        ushort4 p = *((const ushort4*)(Xebf + (size_t)eid_sorted[m] * NH) + l16);
        ax += bf2f(p.x); ay += bf2f(p.y); az += bf2f(p.z); aw += bf2f(p.w);
    }
    float dv = degV[v];
    ax *= dv; ay *= dv; az *= dv; aw *= dv;
    float sq = ax * ax + ay * ay + az * az + aw * aw;
#pragma unroll
    for (int o = 1; o < 16; o <<= 1) sq += __shfl_xor(sq, o);
    float norm = sqrtf(sq);
    float inv = norm > 0.f ? 1.f / norm : 0.f;
    float4 x04 = *((const float4*)(X0 + (size_t)v * NH) + l16);
    float4 xi;
    xi.x = 0.9f * ax * inv + 0.1f * x04.x;
    xi.y = 0.9f * ay * inv + 0.1f * x04.y;
    xi.z = 0.9f * az * inv + 0.1f * x04.z;
    xi.w = 0.9f * aw * inv + 0.1f * x04.w;
    *((float4*)&xis[r][0] + l16) = xi;
    __syncthreads();
    float4 g = {0.f, 0.f, 0.f, 0.f};
#pragma unroll 8
    for (int j = 0; j < NH; ++j) {
        float xj = xis[r][j];
        float4 wv = *((const float4*)&w[j * NH] + l16);
        g.x += xj * wv.x; g.y += xj * wv.y;
        g.z += xj * wv.z; g.w += xj * wv.w;
    }
    float ob = 1.f - beta;
    float o0 = ob * xi.x + beta * g.x;
    float o1 = ob * xi.y + beta * g.y;
    float o2 = ob * xi.z + beta * g.z;
    float o3 = ob * xi.w + beta * g.w;
    o0 = o0 > 0.f ? o0 : 0.f;
    o1 = o1 > 0.f ? o1 : 0.f;
    o2 = o2 > 0.f ? o2 : 0.f;
    o3 = o3 > 0.f ? o3 : 0.f;
    *((ushort4*)(Xbf + (size_t)v * NH) + l16) = pack4(o0, o1, o2, o3);
}

// ---------------- logits = X @ Wout + bout ; log_softmax (16 rows/block) -------
__global__ __launch_bounds__(256) void output_kernel(const unsigned short* __restrict__ Xbf,
                                                     const float* __restrict__ Wout,
                                                     const float* __restrict__ bout,
                                                     float* __restrict__ out) {
    __shared__ float w[NH * NC];         // 10 KB
    __shared__ float xs[16][NH + 4];
    const int tid = threadIdx.x;
    const int lane = tid & 63;
    const int wid  = tid >> 6;
    for (int i = tid; i < NH * NC; i += 256) w[i] = Wout[i];
    const int vbase = blockIdx.x * 16;    // grid = NV/16 exact
    {
        int r = tid >> 4, c = tid & 15;
        ushort4 u = *((const ushort4*)(Xbf + (size_t)(vbase + r) * NH) + c);
        xs[r][c * 4 + 0] = bf2f(u.x);
        xs[r][c * 4 + 1] = bf2f(u.y);
        xs[r][c * 4 + 2] = bf2f(u.z);
        xs[r][c * 4 + 3] = bf2f(u.w);
    }
    __syncthreads();
    for (int q = 0; q < 4; ++q) {
        const int r = wid * 4 + q;
        float logit = -INFINITY;
        if (lane < NC) {
            float acc = bout[lane];
#pragma unroll 8
            for (int j = 0; j < NH; ++j) acc += xs[r][j] * w[j * NC + lane];
            logit = acc;
        }
        float mx = logit;
#pragma unroll
        for (int o = 32; o; o >>= 1) { float t = __shfl_xor(mx, o); mx = t > mx ? t : mx; }
        float e = lane < NC ? expf(logit - mx) : 0.f;
        float s = e;
#pragma unroll
        for (int o = 32; o; o >>= 1) s += __shfl_xor(s, o);
        if (lane < NC) out[(size_t)(vbase + r) * NC + lane] = logit - mx - logf(s);
    }
}

extern "C" void kernel_launch(void* const* d_in, const int* in_sizes, int n_in,
                              void* d_out, int out_size, void* d_ws, size_t ws_size,
                              hipStream_t stream) {
    const float* x    = (const float*)d_in[0];
    const float* degE = (const float*)d_in[1];
    const float* degV = (const float*)d_in[2];
    const float* W0   = (const float*)d_in[3];
    const float* b0   = (const float*)d_in[4];
    const float* Ws   = (const float*)d_in[5];
    const float* Wout = (const float*)d_in[6];
    const float* bout = (const float*)d_in[7];
    const int* vertex = (const int*)d_in[8];
    const int* edges  = (const int*)d_in[9];
    float* out = (float*)d_out;

    // workspace layout
    float* ws = (float*)d_ws;
    float* X0     = ws;                                  // NV*NH fp32 = 25.6 MB
    float* scaleE = X0 + (size_t)NV * NH;                // 20k
    unsigned short* Xbf  = (unsigned short*)(scaleE + NEg);   // NV*NH bf16 = 12.8 MB
    unsigned short* Xebf = Xbf + (size_t)NV * NH;             // NE*NH bf16 = 2.56 MB
    int* cnt_be = (int*)(Xebf + (size_t)NEg * NH);
    int* cnt_bv = cnt_be + NBE;
    int* gcur_e = cnt_bv + NBV;
    int* gcur_v = gcur_e + NBE;
    int* rsb_e  = gcur_v + NBV;
    int* rsb_v  = rsb_e + (NBE + 1);
    int* rs_e   = rsb_v + (NBV + 1);
    int* rs_v   = rs_e + (NEg + 1);
    int* vid_sorted = rs_v + (NV + 1);                   // 6.4 MB
    int* eid_sorted = vid_sorted + NNZp;                 // 6.4 MB

    // ---- CSR build ----
    hipMemsetAsync(cnt_be, 0, (size_t)(NBE + NBV) * 2 * sizeof(int), stream);
    coarse_hist<<<(NNZp + 4095) / 4096, 256, 0, stream>>>(vertex, edges, cnt_be, cnt_bv);
    scan_buckets<<<2, 512, 0, stream>>>(cnt_be, cnt_bv, rsb_e, rsb_v, rs_e, rs_v);
    partition_k<6, NBE><<<PBLK, 256, 0, stream>>>(edges, vertex, rsb_e, gcur_e, vid_sorted);
    partition_k<8, NBV><<<PBLK, 256, 0, stream>>>(vertex, edges, rsb_v, gcur_v, eid_sorted);
    local_sort_k<CAP_E, 6, NEg, true><<<NBE, 256, 0, stream>>>(rsb_e, vid_sorted, rs_e,
                                                               degE, scaleE);
    local_sort_k<CAP_V, 8, NV, false><<<NBV, 256, 0, stream>>>(rsb_v, eid_sorted, rs_v,
                                                               nullptr, nullptr);

    // ---- X = relu(x @ W0 + b0) ----
    gemm0_kernel<<<NV / 16, 256, 0, stream>>>(x, W0, b0, Xbf, X0);

    const float betas[4] = {logf(0.5f / 1.f + 1.f), logf(0.5f / 2.f + 1.f),
                            logf(0.5f / 3.f + 1.f), logf(0.5f / 4.f + 1.f)};

    for (int i = 0; i < 4; ++i) {
        gather_ve<<<NEg / 16, 256, 0, stream>>>(rs_e, vid_sorted, Xbf, scaleE, Xebf);
        gather_ev_update<<<NV / 16, 256, 0, stream>>>(rs_v, eid_sorted, Xebf, degV, X0,
                                                      Ws + (size_t)i * NH * NH, Xbf, betas[i]);
    }

    output_kernel<<<NV / 16, 256, 0, stream>>>(Xbf, Wout, bout, out);
}

// Round 6
// 586.590 us; speedup vs baseline: 5.8043x; 1.0489x over previous
//
#include <hip/hip_runtime.h>
#include <math.h>

constexpr int NV   = 100000;
constexpr int NEg  = 20000;
constexpr int NNZp = 1600000;
constexpr int NF   = 128;
constexpr int NH   = 64;
constexpr int NC   = 40;

constexpr int WE  = 64;                       // e-bucket width
constexpr int NBE = (NEg + WE - 1) / WE;      // 313
constexpr int WV  = 256;                      // v-bucket width
constexpr int NBV = (NV + WV - 1) / WV;       // 391
constexpr int CAP_E = 6400;
constexpr int CAP_V = 4864;
constexpr int CH   = 8192;
constexpr int PBLK = (NNZp + CH - 1) / CH;    // 196

// ---- bf16 <-> fp32 helpers (RNE) ----
__device__ __forceinline__ float bf2f(unsigned short u) {
    unsigned int x = ((unsigned int)u) << 16;
    return __builtin_bit_cast(float, x);
}
__device__ __forceinline__ unsigned short f2bf(float f) {
    unsigned int x = __builtin_bit_cast(unsigned int, f);
    x += 0x7fffu + ((x >> 16) & 1u);
    return (unsigned short)(x >> 16);
}
__device__ __forceinline__ ushort4 pack4(float a, float b, float c, float d) {
    ushort4 u; u.x = f2bf(a); u.y = f2bf(b); u.z = f2bf(c); u.w = f2bf(d);
    return u;
}

// ---------------- coarse histograms (bucket granularity only) ----------------
__global__ __launch_bounds__(256) void coarse_hist(const int* __restrict__ vertex,
                                                   const int* __restrict__ edges,
                                                   int* __restrict__ cnt_be,
                                                   int* __restrict__ cnt_bv) {
    __shared__ int he[NBE], hv[NBV];
    for (int i = threadIdx.x; i < NBE; i += 256) he[i] = 0;
    for (int i = threadIdx.x; i < NBV; i += 256) hv[i] = 0;
    __syncthreads();
    const int base = blockIdx.x * 4096;
    const int end  = min(base + 4096, NNZp);
    for (int i = base + threadIdx.x; i < end; i += 256) {
        atomicAdd(&he[edges[i]  >> 6], 1);
        atomicAdd(&hv[vertex[i] >> 8], 1);
    }
    __syncthreads();
    for (int i = threadIdx.x; i < NBE; i += 256) if (he[i]) atomicAdd(&cnt_be[i], he[i]);
    for (int i = threadIdx.x; i < NBV; i += 256) if (hv[i]) atomicAdd(&cnt_bv[i], hv[i]);
}

// ---------------- tiny bucket scans ----------------
__global__ __launch_bounds__(512) void scan_buckets(const int* __restrict__ cnt_be,
                                                    const int* __restrict__ cnt_bv,
                                                    int* __restrict__ rsb_e,
                                                    int* __restrict__ rsb_v,
                                                    int* __restrict__ rs_e,
                                                    int* __restrict__ rs_v) {
    __shared__ int s[512];
    const int n      = (blockIdx.x == 0) ? NBE : NBV;
    const int* c     = (blockIdx.x == 0) ? cnt_be : cnt_bv;
    int* r           = (blockIdx.x == 0) ? rsb_e : rsb_v;
    const int t = threadIdx.x;
    int v = (t < n) ? c[t] : 0;
    s[t] = v;
    __syncthreads();
    for (int o = 1; o < 512; o <<= 1) {
        int u = (t >= o) ? s[t - o] : 0;
        __syncthreads();
        s[t] += u;
        __syncthreads();
    }
    if (t < n) r[t] = s[t] - v;
    if (t == 0) {
        r[n] = NNZp;
        if (blockIdx.x == 0) rs_e[NEg] = NNZp;
        else                 rs_v[NV]  = NNZp;
    }
}

// ---------------- partition with per-block run reservation --------------------
template <int FB, int NBUCK>
__global__ __launch_bounds__(256) void partition_k(const int* __restrict__ key,
                                                   const int* __restrict__ val,
                                                   const int* __restrict__ rsb,
                                                   int* __restrict__ gcur,
                                                   int* __restrict__ outbuf) {
    __shared__ int cur[NBUCK];
    for (int i = threadIdx.x; i < NBUCK; i += 256) cur[i] = 0;
    __syncthreads();
    const int base = blockIdx.x * CH;
    const int end  = min(base + CH, NNZp);
    for (int i = base + threadIdx.x; i < end; i += 256)
        atomicAdd(&cur[key[i] >> FB], 1);
    __syncthreads();
    for (int i = threadIdx.x; i < NBUCK; i += 256) {
        int h = cur[i];
        cur[i] = rsb[i] + (h ? atomicAdd(&gcur[i], h) : 0);
    }
    __syncthreads();
    for (int i = base + threadIdx.x; i < end; i += 256) {
        int k = key[i];
        int b = k >> FB;
        int pos = atomicAdd(&cur[b], 1);
        outbuf[pos] = (val[i] << FB) | (k & ((1 << FB) - 1));
    }
}

// ---------------- per-bucket LDS counting sort; emits rs (+scaleE) ------------
template <int CAP, int FB, int NID, bool DO_SCALE>
__global__ __launch_bounds__(256) void local_sort_k(const int* __restrict__ rsb,
                                                    int* __restrict__ buf,
                                                    int* __restrict__ rs,
                                                    const float* __restrict__ degE,
                                                    float* __restrict__ scaleE) {
    constexpr int W = 1 << FB;
    __shared__ int stage[CAP];
    __shared__ int hist[W], off[W], cnt2[W];
    const int b = blockIdx.x;
    const int base = rsb[b];
    const int sz   = rsb[b + 1] - base;
    const int tid = threadIdx.x;
    for (int i = tid; i < W; i += 256) { hist[i] = 0; cnt2[i] = 0; }
    __syncthreads();
    for (int t = tid; t < sz; t += 256) atomicAdd(&hist[buf[base + t] & (W - 1)], 1);
    __syncthreads();
    {
        int v = (tid < W) ? hist[tid] : 0;
        if (tid < W) off[tid] = v;
        __syncthreads();
        for (int o = 1; o < W; o <<= 1) {
            int u = (tid < W && tid >= o) ? off[tid - o] : 0;
            __syncthreads();
            if (tid < W) off[tid] += u;
            __syncthreads();
        }
        if (tid < W) off[tid] -= v;
    }
    if (tid < W) {
        int gid = b * W + tid;
        if (gid < NID) {
            rs[gid] = base + off[tid];
            if (DO_SCALE) {
                int c = hist[tid];
                scaleE[gid] = degE[gid] / (float)(c < 1 ? 1 : c);
            }
        }
    }
    __syncthreads();
    for (int t = tid; t < sz; t += 256) {
        int w = buf[base + t];
        int f = w & (W - 1);
        int rk = off[f] + atomicAdd(&cnt2[f], 1);
        stage[rk] = w >> FB;
    }
    __syncthreads();
    for (int t = tid; t < sz; t += 256) buf[base + t] = stage[t];
}

// ---------------- X = relu(x @ W0 + b0); Xbf = X0bf = bf16(X) -----------------
__global__ __launch_bounds__(256) void gemm0_kernel(const float* __restrict__ x,
                                                    const float* __restrict__ W0,
                                                    const float* __restrict__ b0,
                                                    unsigned short* __restrict__ Xbf,
                                                    unsigned short* __restrict__ X0bf) {
    __shared__ float w[NF * NH];          // 32 KB
    __shared__ float xr[16][NF + 4];
    const int tid = threadIdx.x;
    const int l16 = tid & 15;
    const int r   = tid >> 4;
    for (int i = tid; i < NF * NH; i += 256) w[i] = W0[i];
    const int row = blockIdx.x * 16 + r;      // grid = NV/16 exact
    float4 a0 = *((const float4*)(x + (size_t)row * NF) + l16);
    float4 a1 = *((const float4*)(x + (size_t)row * NF + 64) + l16);
    *((float4*)&xr[r][0] + l16)  = a0;
    *((float4*)&xr[r][64] + l16) = a1;
    __syncthreads();
    float4 acc = *((const float4*)b0 + l16);
#pragma unroll 8
    for (int j = 0; j < NF; ++j) {
        float xj = xr[r][j];
        float4 wv = *((const float4*)&w[j * NH] + l16);
        acc.x += xj * wv.x; acc.y += xj * wv.y;
        acc.z += xj * wv.z; acc.w += xj * wv.w;
    }
    acc.x = acc.x > 0.f ? acc.x : 0.f;
    acc.y = acc.y > 0.f ? acc.y : 0.f;
    acc.z = acc.z > 0.f ? acc.z : 0.f;
    acc.w = acc.w > 0.f ? acc.w : 0.f;
    ushort4 p = pack4(acc.x, acc.y, acc.z, acc.w);
    *((ushort4*)(Xbf  + (size_t)row * NH) + l16) = p;
    *((ushort4*)(X0bf + (size_t)row * NH) + l16) = p;
}

// ---------------- v->e gather: Xe[e] = scaleE[e] * sum X[v]  (bf16 rows) -------
__global__ __launch_bounds__(256) void gather_ve(const int* __restrict__ rs_e,
                                                 const int* __restrict__ vid_sorted,
                                                 const unsigned short* __restrict__ Xbf,
                                                 const float* __restrict__ scaleE,
                                                 unsigned short* __restrict__ Xebf) {
    const int tid = threadIdx.x;
    const int l16 = tid & 15;
    const int e = blockIdx.x * 16 + (tid >> 4);   // grid = NE/16 exact
    const int b  = rs_e[e];
    const int en = rs_e[e + 1];
    float ax = 0.f, ay = 0.f, az = 0.f, aw = 0.f;
    int m = b;
    for (; m + 4 <= en; m += 4) {
        int i0 = vid_sorted[m];
        int i1 = vid_sorted[m + 1];
        int i2 = vid_sorted[m + 2];
        int i3 = vid_sorted[m + 3];
        ushort4 p = *((const ushort4*)(Xbf + (size_t)i0 * NH) + l16);
        ushort4 q = *((const ushort4*)(Xbf + (size_t)i1 * NH) + l16);
        ushort4 u = *((const ushort4*)(Xbf + (size_t)i2 * NH) + l16);
        ushort4 t = *((const ushort4*)(Xbf + (size_t)i3 * NH) + l16);
        ax += bf2f(p.x) + bf2f(q.x) + bf2f(u.x) + bf2f(t.x);
        ay += bf2f(p.y) + bf2f(q.y) + bf2f(u.y) + bf2f(t.y);
        az += bf2f(p.z) + bf2f(q.z) + bf2f(u.z) + bf2f(t.z);
        aw += bf2f(p.w) + bf2f(q.w) + bf2f(u.w) + bf2f(t.w);
    }
    for (; m < en; ++m) {
        ushort4 p = *((const ushort4*)(Xbf + (size_t)vid_sorted[m] * NH) + l16);
        ax += bf2f(p.x); ay += bf2f(p.y); az += bf2f(p.z); aw += bf2f(p.w);
    }
    float s = scaleE[e];
    *((ushort4*)(Xebf + (size_t)e * NH) + l16) = pack4(ax * s, ay * s, az * s, aw * s);
}

// ---------------- e->v gather fused with normalize/residual/GEMM/relu ----------
// LAST=true additionally fuses  logits = X @ Wout + bout ; log_softmax  and
// skips the Xbf write (final X never touches HBM).
template <bool LAST>
__global__ __launch_bounds__(256) void gather_ev_update(const int* __restrict__ rs_v,
                                                        const int* __restrict__ eid_sorted,
                                                        const unsigned short* __restrict__ Xebf,
                                                        const float* __restrict__ degV,
                                                        const unsigned short* __restrict__ X0bf,
                                                        const float* __restrict__ Wl,
                                                        unsigned short* __restrict__ Xbf,
                                                        float beta,
                                                        const float* __restrict__ Wout,
                                                        const float* __restrict__ bout,
                                                        float* __restrict__ outp) {
    __shared__ float w[NH * NH];         // 16 KB
    __shared__ float xis[16][NH + 4];    // padded
    constexpr int WOSZ = LAST ? NH * NC : 4;
    __shared__ float wout[WOSZ];         // 10 KB when LAST
    const int tid = threadIdx.x;
    const int l16 = tid & 15;
    const int r   = tid >> 4;
    for (int i = tid; i < NH * NH; i += 256) w[i] = Wl[i];
    if (LAST) for (int i = tid; i < NH * NC; i += 256) wout[i] = Wout[i];
    const int v = blockIdx.x * 16 + r;        // grid = NV/16 exact
    const int b  = rs_v[v];
    const int en = rs_v[v + 1];
    float ax = 0.f, ay = 0.f, az = 0.f, aw = 0.f;
    int m = b;
    for (; m + 4 <= en; m += 4) {
        int i0 = eid_sorted[m];
        int i1 = eid_sorted[m + 1];
        int i2 = eid_sorted[m + 2];
        int i3 = eid_sorted[m + 3];
        ushort4 p = *((const ushort4*)(Xebf + (size_t)i0 * NH) + l16);
        ushort4 q = *((const ushort4*)(Xebf + (size_t)i1 * NH) + l16);
        ushort4 u = *((const ushort4*)(Xebf + (size_t)i2 * NH) + l16);
        ushort4 t = *((const ushort4*)(Xebf + (size_t)i3 * NH) + l16);
        ax += bf2f(p.x) + bf2f(q.x) + bf2f(u.x) + bf2f(t.x);
        ay += bf2f(p.y) + bf2f(q.y) + bf2f(u.y) + bf2f(t.y);
        az += bf2f(p.z) + bf2f(q.z) + bf2f(u.z) + bf2f(t.z);
        aw += bf2f(p.w) + bf2f(q.w) + bf2f(u.w) + bf2f(t.w);
    }
    for (; m < en; ++m) {
        ushort4 p = *((const ushort4*)(Xebf + (size_t)eid_sorted[m] * NH) + l16);
        ax += bf2f(p.x); ay += bf2f(p.y); az += bf2f(p.z); aw += bf2f(p.w);
    }
    float dv = degV[v];
    ax *= dv; ay *= dv; az *= dv; aw *= dv;
    float sq = ax * ax + ay * ay + az * az + aw * aw;
#pragma unroll
    for (int o = 1; o < 16; o <<= 1) sq += __shfl_xor(sq, o);
    float norm = sqrtf(sq);
    float inv = norm > 0.f ? 1.f / norm : 0.f;
    ushort4 u0 = *((const ushort4*)(X0bf + (size_t)v * NH) + l16);
    float4 xi;
    xi.x = 0.9f * ax * inv + 0.1f * bf2f(u0.x);
    xi.y = 0.9f * ay * inv + 0.1f * bf2f(u0.y);
    xi.z = 0.9f * az * inv + 0.1f * bf2f(u0.z);
    xi.w = 0.9f * aw * inv + 0.1f * bf2f(u0.w);
    *((float4*)&xis[r][0] + l16) = xi;
    __syncthreads();
    float4 g = {0.f, 0.f, 0.f, 0.f};
#pragma unroll 8
    for (int j = 0; j < NH; ++j) {
        float xj = xis[r][j];
        float4 wv = *((const float4*)&w[j * NH] + l16);
        g.x += xj * wv.x; g.y += xj * wv.y;
        g.z += xj * wv.z; g.w += xj * wv.w;
    }
    float ob = 1.f - beta;
    float o0 = ob * xi.x + beta * g.x;
    float o1 = ob * xi.y + beta * g.y;
    float o2 = ob * xi.z + beta * g.z;
    float o3 = ob * xi.w + beta * g.w;
    o0 = o0 > 0.f ? o0 : 0.f;
    o1 = o1 > 0.f ? o1 : 0.f;
    o2 = o2 > 0.f ? o2 : 0.f;
    o3 = o3 > 0.f ? o3 : 0.f;
    if (!LAST) {
        *((ushort4*)(Xbf + (size_t)v * NH) + l16) = pack4(o0, o1, o2, o3);
    } else {
        // final X -> LDS (reuse xis), then fused logits + log_softmax
        __syncthreads();                       // all GEMM reads of xis done
        float4 o4 = {o0, o1, o2, o3};
        *((float4*)&xis[r][0] + l16) = o4;
        __syncthreads();
        const int lane = tid & 63;
        const int wid  = tid >> 6;
        const int r0 = wid * 4;                // this wave's 4 rows
        const bool act = lane < NC;
        float a0, a1, a2, a3;
        a0 = a1 = a2 = a3 = act ? bout[lane] : -INFINITY;
        if (act) {
#pragma unroll 8
            for (int j = 0; j < NH; ++j) {
                float wv = wout[j * NC + lane];
                a0 += xis[r0 + 0][j] * wv;
                a1 += xis[r0 + 1][j] * wv;
                a2 += xis[r0 + 2][j] * wv;
                a3 += xis[r0 + 3][j] * wv;
            }
        }
        float m0 = a0, m1 = a1, m2 = a2, m3 = a3;
#pragma unroll
        for (int o = 32; o; o >>= 1) {
            m0 = fmaxf(m0, __shfl_xor(m0, o));
            m1 = fmaxf(m1, __shfl_xor(m1, o));
            m2 = fmaxf(m2, __shfl_xor(m2, o));
            m3 = fmaxf(m3, __shfl_xor(m3, o));
        }
        float e0 = act ? expf(a0 - m0) : 0.f;
        float e1 = act ? expf(a1 - m1) : 0.f;
        float e2 = act ? expf(a2 - m2) : 0.f;
        float e3 = act ? expf(a3 - m3) : 0.f;
#pragma unroll
        for (int o = 32; o; o >>= 1) {
            e0 += __shfl_xor(e0, o);
            e1 += __shfl_xor(e1, o);
            e2 += __shfl_xor(e2, o);
            e3 += __shfl_xor(e3, o);
        }
        if (act) {
            const size_t vb = (size_t)(blockIdx.x * 16 + r0) * NC + lane;
            outp[vb + 0 * NC] = a0 - m0 - logf(e0);
            outp[vb + 1 * NC] = a1 - m1 - logf(e1);
            outp[vb + 2 * NC] = a2 - m2 - logf(e2);
            outp[vb + 3 * NC] = a3 - m3 - logf(e3);
        }
    }
}

extern "C" void kernel_launch(void* const* d_in, const int* in_sizes, int n_in,
                              void* d_out, int out_size, void* d_ws, size_t ws_size,
                              hipStream_t stream) {
    const float* x    = (const float*)d_in[0];
    const float* degE = (const float*)d_in[1];
    const float* degV = (const float*)d_in[2];
    const float* W0   = (const float*)d_in[3];
    const float* b0   = (const float*)d_in[4];
    const float* Ws   = (const float*)d_in[5];
    const float* Wout = (const float*)d_in[6];
    const float* bout = (const float*)d_in[7];
    const int* vertex = (const int*)d_in[8];
    const int* edges  = (const int*)d_in[9];
    float* out = (float*)d_out;

    // workspace layout
    float* scaleE = (float*)d_ws;                              // NEg
    unsigned short* Xbf  = (unsigned short*)(scaleE + NEg);    // NV*NH bf16 = 12.8 MB
    unsigned short* X0bf = Xbf + (size_t)NV * NH;              // 12.8 MB
    unsigned short* Xebf = X0bf + (size_t)NV * NH;             // NE*NH bf16 = 2.56 MB
    int* cnt_be = (int*)(Xebf + (size_t)NEg * NH);
    int* cnt_bv = cnt_be + NBE;
    int* gcur_e = cnt_bv + NBV;
    int* gcur_v = gcur_e + NBE;
    int* rsb_e  = gcur_v + NBV;
    int* rsb_v  = rsb_e + (NBE + 1);
    int* rs_e   = rsb_v + (NBV + 1);
    int* rs_v   = rs_e + (NEg + 1);
    int* vid_sorted = rs_v + (NV + 1);                         // 6.4 MB
    int* eid_sorted = vid_sorted + NNZp;                       // 6.4 MB

    // ---- CSR build ----
    hipMemsetAsync(cnt_be, 0, (size_t)(NBE + NBV) * 2 * sizeof(int), stream);
    coarse_hist<<<(NNZp + 4095) / 4096, 256, 0, stream>>>(vertex, edges, cnt_be, cnt_bv);
    scan_buckets<<<2, 512, 0, stream>>>(cnt_be, cnt_bv, rsb_e, rsb_v, rs_e, rs_v);
    partition_k<6, NBE><<<PBLK, 256, 0, stream>>>(edges, vertex, rsb_e, gcur_e, vid_sorted);
    partition_k<8, NBV><<<PBLK, 256, 0, stream>>>(vertex, edges, rsb_v, gcur_v, eid_sorted);
    local_sort_k<CAP_E, 6, NEg, true><<<NBE, 256, 0, stream>>>(rsb_e, vid_sorted, rs_e,
                                                               degE, scaleE);
    local_sort_k<CAP_V, 8, NV, false><<<NBV, 256, 0, stream>>>(rsb_v, eid_sorted, rs_v,
                                                               nullptr, nullptr);

    // ---- X = relu(x @ W0 + b0) ----
    gemm0_kernel<<<NV / 16, 256, 0, stream>>>(x, W0, b0, Xbf, X0bf);

    const float betas[4] = {logf(0.5f / 1.f + 1.f), logf(0.5f / 2.f + 1.f),
                            logf(0.5f / 3.f + 1.f), logf(0.5f / 4.f + 1.f)};

    for (int i = 0; i < 3; ++i) {
        gather_ve<<<NEg / 16, 256, 0, stream>>>(rs_e, vid_sorted, Xbf, scaleE, Xebf);
        gather_ev_update<false><<<NV / 16, 256, 0, stream>>>(rs_v, eid_sorted, Xebf, degV,
                                                             X0bf, Ws + (size_t)i * NH * NH,
                                                             Xbf, betas[i],
                                                             nullptr, nullptr, nullptr);
    }
    // last layer: ev-gather + update + fused output head
    gather_ve<<<NEg / 16, 256, 0, stream>>>(rs_e, vid_sorted, Xbf, scaleE, Xebf);
    gather_ev_update<true><<<NV / 16, 256, 0, stream>>>(rs_v, eid_sorted, Xebf, degV,
                                                        X0bf, Ws + (size_t)3 * NH * NH,
                                                        Xbf, betas[3],
                                                        Wout, bout, out);
}

// Round 7
// 550.466 us; speedup vs baseline: 6.1852x; 1.0656x over previous
//
#include <hip/hip_runtime.h>
#include <math.h>

constexpr int NV   = 100000;
constexpr int NEg  = 20000;
constexpr int NNZp = 1600000;
constexpr int NF   = 128;
constexpr int NH   = 64;
constexpr int NC   = 40;

constexpr int WE  = 64;                       // e-bucket width (2^6)
constexpr int NBE = (NEg + WE - 1) / WE;      // 313
constexpr int WV  = 256;                      // v-bucket width (2^8)
constexpr int NBV = (NV + WV - 1) / WV;       // 391
constexpr int CAPS = 6400;                    // shared stage cap (max bucket ~5500)
constexpr int CH   = 2048;                    // partition chunk per block
constexpr int PBLK = (NNZp + CH - 1) / CH;    // 782

// ---- bf16 <-> fp32 helpers (RNE) ----
__device__ __forceinline__ float bf2f(unsigned short u) {
    unsigned int x = ((unsigned int)u) << 16;
    return __builtin_bit_cast(float, x);
}
__device__ __forceinline__ unsigned short f2bf(float f) {
    unsigned int x = __builtin_bit_cast(unsigned int, f);
    x += 0x7fffu + ((x >> 16) & 1u);
    return (unsigned short)(x >> 16);
}
__device__ __forceinline__ ushort4 pack4(float a, float b, float c, float d) {
    ushort4 u; u.x = f2bf(a); u.y = f2bf(b); u.z = f2bf(c); u.w = f2bf(d);
    return u;
}

// ---------------- coarse histograms (bucket granularity only) ----------------
__global__ __launch_bounds__(256) void coarse_hist(const int* __restrict__ vertex,
                                                   const int* __restrict__ edges,
                                                   int* __restrict__ cnt_be,
                                                   int* __restrict__ cnt_bv) {
    __shared__ int he[NBE], hv[NBV];
    for (int i = threadIdx.x; i < NBE; i += 256) he[i] = 0;
    for (int i = threadIdx.x; i < NBV; i += 256) hv[i] = 0;
    __syncthreads();
    const int base = blockIdx.x * CH;
    const int end  = min(base + CH, NNZp);
    for (int i = base + threadIdx.x; i < end; i += 256) {
        atomicAdd(&he[edges[i]  >> 6], 1);
        atomicAdd(&hv[vertex[i] >> 8], 1);
    }
    __syncthreads();
    for (int i = threadIdx.x; i < NBE; i += 256) if (he[i]) atomicAdd(&cnt_be[i], he[i]);
    for (int i = threadIdx.x; i < NBV; i += 256) if (hv[i]) atomicAdd(&cnt_bv[i], hv[i]);
}

// ---------------- tiny bucket scans ----------------
__global__ __launch_bounds__(512) void scan_buckets(const int* __restrict__ cnt_be,
                                                    const int* __restrict__ cnt_bv,
                                                    int* __restrict__ rsb_e,
                                                    int* __restrict__ rsb_v,
                                                    int* __restrict__ rs_e,
                                                    int* __restrict__ rs_v) {
    __shared__ int s[512];
    const int n      = (blockIdx.x == 0) ? NBE : NBV;
    const int* c     = (blockIdx.x == 0) ? cnt_be : cnt_bv;
    int* r           = (blockIdx.x == 0) ? rsb_e : rsb_v;
    const int t = threadIdx.x;
    int v = (t < n) ? c[t] : 0;
    s[t] = v;
    __syncthreads();
    for (int o = 1; o < 512; o <<= 1) {
        int u = (t >= o) ? s[t - o] : 0;
        __syncthreads();
        s[t] += u;
        __syncthreads();
    }
    if (t < n) r[t] = s[t] - v;
    if (t == 0) {
        r[n] = NNZp;
        if (blockIdx.x == 0) rs_e[NEg] = NNZp;
        else                 rs_v[NV]  = NNZp;
    }
}

// ------- fused partition: both sides, indices staged in LDS, one global read ---
__global__ __launch_bounds__(256) void partition_both(const int* __restrict__ vertex,
                                                      const int* __restrict__ edges,
                                                      const int* __restrict__ rsb_e,
                                                      const int* __restrict__ rsb_v,
                                                      int* __restrict__ gcur_e,
                                                      int* __restrict__ gcur_v,
                                                      int* __restrict__ vid_out,
                                                      int* __restrict__ eid_out) {
    __shared__ int se[CH], sv[CH];           // 8 + 8 KB
    __shared__ int cur_e[NBE], cur_v[NBV];   // 1.25 + 1.56 KB
    const int tid = threadIdx.x;
    for (int i = tid; i < NBE; i += 256) cur_e[i] = 0;
    for (int i = tid; i < NBV; i += 256) cur_v[i] = 0;
    __syncthreads();
    const int base = blockIdx.x * CH;
    const int n    = min(base + CH, NNZp) - base;
    for (int i = tid; i < n; i += 256) {
        int e = edges[base + i];
        int v = vertex[base + i];
        se[i] = e; sv[i] = v;
        atomicAdd(&cur_e[e >> 6], 1);
        atomicAdd(&cur_v[v >> 8], 1);
    }
    __syncthreads();
    for (int i = tid; i < NBE; i += 256) {
        int h = cur_e[i];
        cur_e[i] = rsb_e[i] + (h ? atomicAdd(&gcur_e[i], h) : 0);
    }
    for (int i = tid; i < NBV; i += 256) {
        int h = cur_v[i];
        cur_v[i] = rsb_v[i] + (h ? atomicAdd(&gcur_v[i], h) : 0);
    }
    __syncthreads();
    for (int i = tid; i < n; i += 256) {
        int e = se[i], v = sv[i];
        int pe = atomicAdd(&cur_e[e >> 6], 1);
        vid_out[pe] = (v << 6) | (e & 63);      // v<=99999: 17+6=23 bits
        int pv = atomicAdd(&cur_v[v >> 8], 1);
        eid_out[pv] = (e << 8) | (v & 255);     // e<=19999: 15+8=23 bits
    }
}

// ------- fused per-bucket LDS counting sort (e-blocks then v-blocks) ----------
// emits per-id CSR offsets (+scaleE on the e side)
__global__ __launch_bounds__(512) void local_sort_both(const int* __restrict__ rsb_e,
                                                       const int* __restrict__ rsb_v,
                                                       int* __restrict__ vid_buf,
                                                       int* __restrict__ eid_buf,
                                                       int* __restrict__ rs_e,
                                                       int* __restrict__ rs_v,
                                                       const float* __restrict__ degE,
                                                       float* __restrict__ scaleE) {
    __shared__ int stage[CAPS];              // 25.6 KB
    __shared__ int hist[256], off[256], cnt2[256];
    const bool eside = blockIdx.x < NBE;
    const int b   = eside ? blockIdx.x : blockIdx.x - NBE;
    const int W   = eside ? 64 : 256;
    const int FB  = eside ? 6 : 8;
    const int NID = eside ? NEg : NV;
    const int* rsb = eside ? rsb_e : rsb_v;
    int* buf       = eside ? vid_buf : eid_buf;
    int* rs        = eside ? rs_e : rs_v;
    const int base = rsb[b];
    const int sz   = rsb[b + 1] - base;
    const int tid = threadIdx.x;
    if (tid < 256) { hist[tid] = 0; cnt2[tid] = 0; }
    __syncthreads();
    for (int t = tid; t < sz; t += 512) atomicAdd(&hist[buf[base + t] & (W - 1)], 1);
    __syncthreads();
    {
        int v = (tid < W) ? hist[tid] : 0;
        if (tid < W) off[tid] = v;
        __syncthreads();
        for (int o = 1; o < W; o <<= 1) {
            int u = (tid < W && tid >= o) ? off[tid - o] : 0;
            __syncthreads();
            if (tid < W) off[tid] += u;
            __syncthreads();
        }
        if (tid < W) off[tid] -= v;
    }
    if (tid < W) {
        int gid = b * W + tid;
        if (gid < NID) {
            rs[gid] = base + off[tid];
            if (eside) {
                int c = hist[tid];
                scaleE[gid] = degE[gid] / (float)(c < 1 ? 1 : c);
            }
        }
    }
    __syncthreads();
    for (int t = tid; t < sz; t += 512) {
        int w = buf[base + t];
        int f = w & (W - 1);
        int rk = off[f] + atomicAdd(&cnt2[f], 1);
        stage[rk] = w >> FB;
    }
    __syncthreads();
    for (int t = tid; t < sz; t += 512) buf[base + t] = stage[t];
}

// ---------------- X = relu(x @ W0 + b0); Xbf = X0bf = bf16(X) -----------------
__global__ __launch_bounds__(256) void gemm0_kernel(const float* __restrict__ x,
                                                    const float* __restrict__ W0,
                                                    const float* __restrict__ b0,
                                                    unsigned short* __restrict__ Xbf,
                                                    unsigned short* __restrict__ X0bf) {
    __shared__ float w[NF * NH];          // 32 KB
    __shared__ float xr[16][NF + 4];
    const int tid = threadIdx.x;
    const int l16 = tid & 15;
    const int r   = tid >> 4;
    for (int i = tid; i < NF * NH; i += 256) w[i] = W0[i];
    const int row = blockIdx.x * 16 + r;      // grid = NV/16 exact
    float4 a0 = *((const float4*)(x + (size_t)row * NF) + l16);
    float4 a1 = *((const float4*)(x + (size_t)row * NF + 64) + l16);
    *((float4*)&xr[r][0] + l16)  = a0;
    *((float4*)&xr[r][64] + l16) = a1;
    __syncthreads();
    float4 acc = *((const float4*)b0 + l16);
#pragma unroll 8
    for (int j = 0; j < NF; ++j) {
        float xj = xr[r][j];
        float4 wv = *((const float4*)&w[j * NH] + l16);
        acc.x += xj * wv.x; acc.y += xj * wv.y;
        acc.z += xj * wv.z; acc.w += xj * wv.w;
    }
    acc.x = acc.x > 0.f ? acc.x : 0.f;
    acc.y = acc.y > 0.f ? acc.y : 0.f;
    acc.z = acc.z > 0.f ? acc.z : 0.f;
    acc.w = acc.w > 0.f ? acc.w : 0.f;
    ushort4 p = pack4(acc.x, acc.y, acc.z, acc.w);
    *((ushort4*)(Xbf  + (size_t)row * NH) + l16) = p;
    *((ushort4*)(X0bf + (size_t)row * NH) + l16) = p;
}

// ---------------- v->e gather (idx software-pipelined) -------------------------
__global__ __launch_bounds__(256) void gather_ve(const int* __restrict__ rs_e,
                                                 const int* __restrict__ vid_sorted,
                                                 const unsigned short* __restrict__ Xbf,
                                                 const float* __restrict__ scaleE,
                                                 unsigned short* __restrict__ Xebf) {
    const int tid = threadIdx.x;
    const int l16 = tid & 15;
    const int e = blockIdx.x * 16 + (tid >> 4);   // grid = NE/16 exact
    const int b  = rs_e[e];
    const int en = rs_e[e + 1];
    const float s = scaleE[e];
    float ax = 0.f, ay = 0.f, az = 0.f, aw = 0.f;
    int m = b;
    if (m + 4 <= en) {
        int i0 = vid_sorted[m], i1 = vid_sorted[m + 1];
        int i2 = vid_sorted[m + 2], i3 = vid_sorted[m + 3];
        m += 4;
        while (m + 4 <= en) {
            int j0 = vid_sorted[m], j1 = vid_sorted[m + 1];
            int j2 = vid_sorted[m + 2], j3 = vid_sorted[m + 3];
            m += 4;
            ushort4 p = *((const ushort4*)(Xbf + (size_t)i0 * NH) + l16);
            ushort4 q = *((const ushort4*)(Xbf + (size_t)i1 * NH) + l16);
            ushort4 u = *((const ushort4*)(Xbf + (size_t)i2 * NH) + l16);
            ushort4 t = *((const ushort4*)(Xbf + (size_t)i3 * NH) + l16);
            ax += bf2f(p.x) + bf2f(q.x) + bf2f(u.x) + bf2f(t.x);
            ay += bf2f(p.y) + bf2f(q.y) + bf2f(u.y) + bf2f(t.y);
            az += bf2f(p.z) + bf2f(q.z) + bf2f(u.z) + bf2f(t.z);
            aw += bf2f(p.w) + bf2f(q.w) + bf2f(u.w) + bf2f(t.w);
            i0 = j0; i1 = j1; i2 = j2; i3 = j3;
        }
        ushort4 p = *((const ushort4*)(Xbf + (size_t)i0 * NH) + l16);
        ushort4 q = *((const ushort4*)(Xbf + (size_t)i1 * NH) + l16);
        ushort4 u = *((const ushort4*)(Xbf + (size_t)i2 * NH) + l16);
        ushort4 t = *((const ushort4*)(Xbf + (size_t)i3 * NH) + l16);
        ax += bf2f(p.x) + bf2f(q.x) + bf2f(u.x) + bf2f(t.x);
        ay += bf2f(p.y) + bf2f(q.y) + bf2f(u.y) + bf2f(t.y);
        az += bf2f(p.z) + bf2f(q.z) + bf2f(u.z) + bf2f(t.z);
        aw += bf2f(p.w) + bf2f(q.w) + bf2f(u.w) + bf2f(t.w);
    }
    for (; m < en; ++m) {
        ushort4 p = *((const ushort4*)(Xbf + (size_t)vid_sorted[m] * NH) + l16);
        ax += bf2f(p.x); ay += bf2f(p.y); az += bf2f(p.z); aw += bf2f(p.w);
    }
    *((ushort4*)(Xebf + (size_t)e * NH) + l16) = pack4(ax * s, ay * s, az * s, aw * s);
}

// ---------------- e->v gather fused with normalize/residual/GEMM/relu ----------
// LAST=true fuses the output head, overlaying Wout into w[] after the MLP.
template <bool LAST>
__global__ __launch_bounds__(256) void gather_ev_update(const int* __restrict__ rs_v,
                                                        const int* __restrict__ eid_sorted,
                                                        const unsigned short* __restrict__ Xebf,
                                                        const float* __restrict__ degV,
                                                        const unsigned short* __restrict__ X0bf,
                                                        const float* __restrict__ Wl,
                                                        unsigned short* __restrict__ Xbf,
                                                        float beta,
                                                        const float* __restrict__ Wout,
                                                        const float* __restrict__ bout,
                                                        float* __restrict__ outp) {
    __shared__ float w[NH * NH];         // 16 KB (reused for Wout in LAST epilogue)
    __shared__ float xis[16][NH + 4];    // padded
    const int tid = threadIdx.x;
    const int l16 = tid & 15;
    const int r   = tid >> 4;
    for (int i = tid; i < NH * NH; i += 256) w[i] = Wl[i];
    const int v = blockIdx.x * 16 + r;        // grid = NV/16 exact
    const int b  = rs_v[v];
    const int en = rs_v[v + 1];
    const float dv = degV[v];
    float ax = 0.f, ay = 0.f, az = 0.f, aw = 0.f;
    int m = b;
    if (m + 4 <= en) {
        int i0 = eid_sorted[m], i1 = eid_sorted[m + 1];
        int i2 = eid_sorted[m + 2], i3 = eid_sorted[m + 3];
        m += 4;
        while (m + 4 <= en) {
            int j0 = eid_sorted[m], j1 = eid_sorted[m + 1];
            int j2 = eid_sorted[m + 2], j3 = eid_sorted[m + 3];
            m += 4;
            ushort4 p = *((const ushort4*)(Xebf + (size_t)i0 * NH) + l16);
            ushort4 q = *((const ushort4*)(Xebf + (size_t)i1 * NH) + l16);
            ushort4 u = *((const ushort4*)(Xebf + (size_t)i2 * NH) + l16);
            ushort4 t = *((const ushort4*)(Xebf + (size_t)i3 * NH) + l16);
            ax += bf2f(p.x) + bf2f(q.x) + bf2f(u.x) + bf2f(t.x);
            ay += bf2f(p.y) + bf2f(q.y) + bf2f(u.y) + bf2f(t.y);
            az += bf2f(p.z) + bf2f(q.z) + bf2f(u.z) + bf2f(t.z);
            aw += bf2f(p.w) + bf2f(q.w) + bf2f(u.w) + bf2f(t.w);
            i0 = j0; i1 = j1; i2 = j2; i3 = j3;
        }
        ushort4 p = *((const ushort4*)(Xebf + (size_t)i0 * NH) + l16);
        ushort4 q = *((const ushort4*)(Xebf + (size_t)i1 * NH) + l16);
        ushort4 u = *((const ushort4*)(Xebf + (size_t)i2 * NH) + l16);
        ushort4 t = *((const ushort4*)(Xebf + (size_t)i3 * NH) + l16);
        ax += bf2f(p.x) + bf2f(q.x) + bf2f(u.x) + bf2f(t.x);
        ay += bf2f(p.y) + bf2f(q.y) + bf2f(u.y) + bf2f(t.y);
        az += bf2f(p.z) + bf2f(q.z) + bf2f(u.z) + bf2f(t.z);
        aw += bf2f(p.w) + bf2f(q.w) + bf2f(u.w) + bf2f(t.w);
    }
    for (; m < en; ++m) {
        ushort4 p = *((const ushort4*)(Xebf + (size_t)eid_sorted[m] * NH) + l16);
        ax += bf2f(p.x); ay += bf2f(p.y); az += bf2f(p.z); aw += bf2f(p.w);
    }
    ax *= dv; ay *= dv; az *= dv; aw *= dv;
    float sq = ax * ax + ay * ay + az * az + aw * aw;
#pragma unroll
    for (int o = 1; o < 16; o <<= 1) sq += __shfl_xor(sq, o);
    float norm = sqrtf(sq);
    float inv = norm > 0.f ? 1.f / norm : 0.f;
    ushort4 u0 = *((const ushort4*)(X0bf + (size_t)v * NH) + l16);
    float4 xi;
    xi.x = 0.9f * ax * inv + 0.1f * bf2f(u0.x);
    xi.y = 0.9f * ay * inv + 0.1f * bf2f(u0.y);
    xi.z = 0.9f * az * inv + 0.1f * bf2f(u0.z);
    xi.w = 0.9f * aw * inv + 0.1f * bf2f(u0.w);
    *((float4*)&xis[r][0] + l16) = xi;
    __syncthreads();
    float4 g = {0.f, 0.f, 0.f, 0.f};
#pragma unroll 8
    for (int j = 0; j < NH; ++j) {
        float xj = xis[r][j];
        float4 wv = *((const float4*)&w[j * NH] + l16);
        g.x += xj * wv.x; g.y += xj * wv.y;
        g.z += xj * wv.z; g.w += xj * wv.w;
    }
    float ob = 1.f - beta;
    float o0 = ob * xi.x + beta * g.x;
    float o1 = ob * xi.y + beta * g.y;
    float o2 = ob * xi.z + beta * g.z;
    float o3 = ob * xi.w + beta * g.w;
    o0 = o0 > 0.f ? o0 : 0.f;
    o1 = o1 > 0.f ? o1 : 0.f;
    o2 = o2 > 0.f ? o2 : 0.f;
    o3 = o3 > 0.f ? o3 : 0.f;
    if (!LAST) {
        *((ushort4*)(Xbf + (size_t)v * NH) + l16) = pack4(o0, o1, o2, o3);
    } else {
        // all reads of w/xis done -> overlay: final X into xis, Wout into w
        __syncthreads();
        float4 o4 = {o0, o1, o2, o3};
        *((float4*)&xis[r][0] + l16) = o4;
        for (int i = tid; i < NH * NC; i += 256) w[i] = Wout[i];
        __syncthreads();
        const int lane = tid & 63;
        const int wid  = tid >> 6;
        const int r0 = wid * 4;                // this wave's 4 rows
        const bool act = lane < NC;
        float a0, a1, a2, a3;
        a0 = a1 = a2 = a3 = act ? bout[lane] : -INFINITY;
        if (act) {
#pragma unroll 8
            for (int j = 0; j < NH; ++j) {
                float wv = w[j * NC + lane];
                a0 += xis[r0 + 0][j] * wv;
                a1 += xis[r0 + 1][j] * wv;
                a2 += xis[r0 + 2][j] * wv;
                a3 += xis[r0 + 3][j] * wv;
            }
        }
        float m0 = a0, m1 = a1, m2 = a2, m3 = a3;
#pragma unroll
        for (int o = 32; o; o >>= 1) {
            m0 = fmaxf(m0, __shfl_xor(m0, o));
            m1 = fmaxf(m1, __shfl_xor(m1, o));
            m2 = fmaxf(m2, __shfl_xor(m2, o));
            m3 = fmaxf(m3, __shfl_xor(m3, o));
        }
        float e0 = act ? expf(a0 - m0) : 0.f;
        float e1 = act ? expf(a1 - m1) : 0.f;
        float e2 = act ? expf(a2 - m2) : 0.f;
        float e3 = act ? expf(a3 - m3) : 0.f;
#pragma unroll
        for (int o = 32; o; o >>= 1) {
            e0 += __shfl_xor(e0, o);
            e1 += __shfl_xor(e1, o);
            e2 += __shfl_xor(e2, o);
            e3 += __shfl_xor(e3, o);
        }
        if (act) {
            const size_t vb = (size_t)(blockIdx.x * 16 + r0) * NC + lane;
            outp[vb + 0 * NC] = a0 - m0 - logf(e0);
            outp[vb + 1 * NC] = a1 - m1 - logf(e1);
            outp[vb + 2 * NC] = a2 - m2 - logf(e2);
            outp[vb + 3 * NC] = a3 - m3 - logf(e3);
        }
    }
}

extern "C" void kernel_launch(void* const* d_in, const int* in_sizes, int n_in,
                              void* d_out, int out_size, void* d_ws, size_t ws_size,
                              hipStream_t stream) {
    const float* x    = (const float*)d_in[0];
    const float* degE = (const float*)d_in[1];
    const float* degV = (const float*)d_in[2];
    const float* W0   = (const float*)d_in[3];
    const float* b0   = (const float*)d_in[4];
    const float* Ws   = (const float*)d_in[5];
    const float* Wout = (const float*)d_in[6];
    const float* bout = (const float*)d_in[7];
    const int* vertex = (const int*)d_in[8];
    const int* edges  = (const int*)d_in[9];
    float* out = (float*)d_out;

    // workspace layout
    float* scaleE = (float*)d_ws;                              // NEg
    unsigned short* Xbf  = (unsigned short*)(scaleE + NEg);    // NV*NH bf16 = 12.8 MB
    unsigned short* X0bf = Xbf + (size_t)NV * NH;              // 12.8 MB
    unsigned short* Xebf = X0bf + (size_t)NV * NH;             // NE*NH bf16 = 2.56 MB
    int* cnt_be = (int*)(Xebf + (size_t)NEg * NH);
    int* cnt_bv = cnt_be + NBE;
    int* gcur_e = cnt_bv + NBV;
    int* gcur_v = gcur_e + NBE;
    int* rsb_e  = gcur_v + NBV;
    int* rsb_v  = rsb_e + (NBE + 1);
    int* rs_e   = rsb_v + (NBV + 1);
    int* rs_v   = rs_e + (NEg + 1);
    int* vid_sorted = rs_v + (NV + 1);                         // 6.4 MB
    int* eid_sorted = vid_sorted + NNZp;                       // 6.4 MB

    // ---- CSR build ----
    hipMemsetAsync(cnt_be, 0, (size_t)(NBE + NBV) * 2 * sizeof(int), stream);
    coarse_hist<<<PBLK, 256, 0, stream>>>(vertex, edges, cnt_be, cnt_bv);
    scan_buckets<<<2, 512, 0, stream>>>(cnt_be, cnt_bv, rsb_e, rsb_v, rs_e, rs_v);
    partition_both<<<PBLK, 256, 0, stream>>>(vertex, edges, rsb_e, rsb_v,
                                             gcur_e, gcur_v, vid_sorted, eid_sorted);
    local_sort_both<<<NBE + NBV, 512, 0, stream>>>(rsb_e, rsb_v, vid_sorted, eid_sorted,
                                                   rs_e, rs_v, degE, scaleE);

    // ---- X = relu(x @ W0 + b0) ----
    gemm0_kernel<<<NV / 16, 256, 0, stream>>>(x, W0, b0, Xbf, X0bf);

    const float betas[4] = {logf(0.5f / 1.f + 1.f), logf(0.5f / 2.f + 1.f),
                            logf(0.5f / 3.f + 1.f), logf(0.5f / 4.f + 1.f)};

    for (int i = 0; i < 3; ++i) {
        gather_ve<<<NEg / 16, 256, 0, stream>>>(rs_e, vid_sorted, Xbf, scaleE, Xebf);
        gather_ev_update<false><<<NV / 16, 256, 0, stream>>>(rs_v, eid_sorted, Xebf, degV,
                                                             X0bf, Ws + (size_t)i * NH * NH,
                                                             Xbf, betas[i],
                                                             nullptr, nullptr, nullptr);
    }
    gather_ve<<<NEg / 16, 256, 0, stream>>>(rs_e, vid_sorted, Xbf, scaleE, Xebf);
    gather_ev_update<true><<<NV / 16, 256, 0, stream>>>(rs_v, eid_sorted, Xebf, degV,
                                                        X0bf, Ws + (size_t)3 * NH * NH,
                                                        Xbf, betas[3],
                                                        Wout, bout, out);
}

// Round 8
// 482.955 us; speedup vs baseline: 7.0499x; 1.1398x over previous
//
#include <hip/hip_runtime.h>
#include <math.h>

constexpr int NV   = 100000;
constexpr int NEg  = 20000;
constexpr int NNZp = 1600000;
constexpr int NF   = 128;
constexpr int NH   = 64;
constexpr int NC   = 40;

constexpr int WE  = 64;                       // e-bucket width (2^6)
constexpr int NBE = (NEg + WE - 1) / WE;      // 313
constexpr int WV  = 256;                      // v-bucket width (2^8)
constexpr int NBV = (NV + WV - 1) / WV;       // 391
constexpr int CAPS = 6400;                    // local_sort stage cap
constexpr int CH   = 2048;                    // partition chunk per block
constexpr int PBLK = (NNZp + CH - 1) / CH;    // 782

typedef __bf16 bf16x8 __attribute__((ext_vector_type(8)));
typedef float  f32x4  __attribute__((ext_vector_type(4)));

// ---- bf16 <-> fp32 helpers (RNE) ----
__device__ __forceinline__ float bf2f(unsigned short u) {
    unsigned int x = ((unsigned int)u) << 16;
    return __builtin_bit_cast(float, x);
}
__device__ __forceinline__ unsigned short f2bf(float f) {
    unsigned int x = __builtin_bit_cast(unsigned int, f);
    x += 0x7fffu + ((x >> 16) & 1u);
    return (unsigned short)(x >> 16);
}
__device__ __forceinline__ ushort4 pack4(float a, float b, float c, float d) {
    ushort4 u; u.x = f2bf(a); u.y = f2bf(b); u.z = f2bf(c); u.w = f2bf(d);
    return u;
}

// ---------------- coarse histograms ----------------
__global__ __launch_bounds__(256) void coarse_hist(const int* __restrict__ vertex,
                                                   const int* __restrict__ edges,
                                                   int* __restrict__ cnt_be,
                                                   int* __restrict__ cnt_bv) {
    __shared__ int he[NBE], hv[NBV];
    for (int i = threadIdx.x; i < NBE; i += 256) he[i] = 0;
    for (int i = threadIdx.x; i < NBV; i += 256) hv[i] = 0;
    __syncthreads();
    const int base = blockIdx.x * CH;
    const int end  = min(base + CH, NNZp);
    for (int i = base + threadIdx.x; i < end; i += 256) {
        atomicAdd(&he[edges[i]  >> 6], 1);
        atomicAdd(&hv[vertex[i] >> 8], 1);
    }
    __syncthreads();
    for (int i = threadIdx.x; i < NBE; i += 256) if (he[i]) atomicAdd(&cnt_be[i], he[i]);
    for (int i = threadIdx.x; i < NBV; i += 256) if (hv[i]) atomicAdd(&cnt_bv[i], hv[i]);
}

// ---------------- tiny bucket scans ----------------
__global__ __launch_bounds__(512) void scan_buckets(const int* __restrict__ cnt_be,
                                                    const int* __restrict__ cnt_bv,
                                                    int* __restrict__ rsb_e,
                                                    int* __restrict__ rsb_v,
                                                    int* __restrict__ rs_e,
                                                    int* __restrict__ rs_v) {
    __shared__ int s[512];
    const int n      = (blockIdx.x == 0) ? NBE : NBV;
    const int* c     = (blockIdx.x == 0) ? cnt_be : cnt_bv;
    int* r           = (blockIdx.x == 0) ? rsb_e : rsb_v;
    const int t = threadIdx.x;
    int v = (t < n) ? c[t] : 0;
    s[t] = v;
    __syncthreads();
    for (int o = 1; o < 512; o <<= 1) {
        int u = (t >= o) ? s[t - o] : 0;
        __syncthreads();
        s[t] += u;
        __syncthreads();
    }
    if (t < n) r[t] = s[t] - v;
    if (t == 0) {
        r[n] = NNZp;
        if (blockIdx.x == 0) rs_e[NEg] = NNZp;
        else                 rs_v[NV]  = NNZp;
    }
}

// ------- fused partition: both sides, indices staged in LDS -------------------
__global__ __launch_bounds__(256) void partition_both(const int* __restrict__ vertex,
                                                      const int* __restrict__ edges,
                                                      const int* __restrict__ rsb_e,
                                                      const int* __restrict__ rsb_v,
                                                      int* __restrict__ gcur_e,
                                                      int* __restrict__ gcur_v,
                                                      int* __restrict__ vid_out,
                                                      int* __restrict__ eid_out) {
    __shared__ int se[CH], sv[CH];
    __shared__ int cur_e[NBE], cur_v[NBV];
    const int tid = threadIdx.x;
    for (int i = tid; i < NBE; i += 256) cur_e[i] = 0;
    for (int i = tid; i < NBV; i += 256) cur_v[i] = 0;
    __syncthreads();
    const int base = blockIdx.x * CH;
    const int n    = min(base + CH, NNZp) - base;
    for (int i = tid; i < n; i += 256) {
        int e = edges[base + i];
        int v = vertex[base + i];
        se[i] = e; sv[i] = v;
        atomicAdd(&cur_e[e >> 6], 1);
        atomicAdd(&cur_v[v >> 8], 1);
    }
    __syncthreads();
    for (int i = tid; i < NBE; i += 256) {
        int h = cur_e[i];
        cur_e[i] = rsb_e[i] + (h ? atomicAdd(&gcur_e[i], h) : 0);
    }
    for (int i = tid; i < NBV; i += 256) {
        int h = cur_v[i];
        cur_v[i] = rsb_v[i] + (h ? atomicAdd(&gcur_v[i], h) : 0);
    }
    __syncthreads();
    for (int i = tid; i < n; i += 256) {
        int e = se[i], v = sv[i];
        int pe = atomicAdd(&cur_e[e >> 6], 1);
        vid_out[pe] = (v << 6) | (e & 63);
        int pv = atomicAdd(&cur_v[v >> 8], 1);
        eid_out[pv] = (e << 8) | (v & 255);
    }
}

// ------- fused per-bucket LDS counting sort -----------------------------------
__global__ __launch_bounds__(512) void local_sort_both(const int* __restrict__ rsb_e,
                                                       const int* __restrict__ rsb_v,
                                                       int* __restrict__ vid_buf,
                                                       int* __restrict__ eid_buf,
                                                       int* __restrict__ rs_e,
                                                       int* __restrict__ rs_v,
                                                       const float* __restrict__ degE,
                                                       float* __restrict__ scaleE) {
    __shared__ int stage[CAPS];
    __shared__ int hist[256], off[256], cnt2[256];
    const bool eside = blockIdx.x < NBE;
    const int b   = eside ? blockIdx.x : blockIdx.x - NBE;
    const int W   = eside ? 64 : 256;
    const int FB  = eside ? 6 : 8;
    const int NID = eside ? NEg : NV;
    const int* rsb = eside ? rsb_e : rsb_v;
    int* buf       = eside ? vid_buf : eid_buf;
    int* rs        = eside ? rs_e : rs_v;
    const int base = rsb[b];
    const int sz   = rsb[b + 1] - base;
    const int tid = threadIdx.x;
    if (tid < 256) { hist[tid] = 0; cnt2[tid] = 0; }
    __syncthreads();
    for (int t = tid; t < sz; t += 512) atomicAdd(&hist[buf[base + t] & (W - 1)], 1);
    __syncthreads();
    {
        int v = (tid < W) ? hist[tid] : 0;
        if (tid < W) off[tid] = v;
        __syncthreads();
        for (int o = 1; o < W; o <<= 1) {
            int u = (tid < W && tid >= o) ? off[tid - o] : 0;
            __syncthreads();
            if (tid < W) off[tid] += u;
            __syncthreads();
        }
        if (tid < W) off[tid] -= v;
    }
    if (tid < W) {
        int gid = b * W + tid;
        if (gid < NID) {
            rs[gid] = base + off[tid];
            if (eside) {
                int c = hist[tid];
                scaleE[gid] = degE[gid] / (float)(c < 1 ? 1 : c);
            }
        }
    }
    __syncthreads();
    for (int t = tid; t < sz; t += 512) {
        int w = buf[base + t];
        int f = w & (W - 1);
        int rk = off[f] + atomicAdd(&cnt2[f], 1);
        stage[rk] = w >> FB;
    }
    __syncthreads();
    for (int t = tid; t < sz; t += 512) buf[base + t] = stage[t];
}

// ------- W fragments (B-operand layout, bf16) for the 4 MLPs + output head ----
// frag group g = ((layer*4 + wave)*2 + khalf) for g<32; head: g=32+wave*2+khalf
// value[lane][j] = W[khalf*32 + (lane>>4)*8 + j][wave*16 + (lane&15)]
__global__ __launch_bounds__(256) void make_wfrag(const float* __restrict__ Ws,
                                                  const float* __restrict__ Wout,
                                                  unsigned short* __restrict__ frag) {
    int t = blockIdx.x * 256 + threadIdx.x;     // 2560 threads exactly
    int lane = t & 63;
    int g = t >> 6;                             // 0..39
    int quad = lane >> 4, cl = lane & 15;
    unsigned short o[8];
    if (g < 32) {
        int li = g >> 3, w = (g >> 1) & 3, kh = g & 1;
        int n = w * 16 + cl;
#pragma unroll
        for (int j = 0; j < 8; ++j) {
            int k = kh * 32 + quad * 8 + j;
            o[j] = f2bf(Ws[(size_t)li * NH * NH + k * NH + n]);
        }
    } else {
        int w = (g - 32) >> 1, kh = g & 1;
        int n = w * 16 + cl;
#pragma unroll
        for (int j = 0; j < 8; ++j) {
            int k = kh * 32 + quad * 8 + j;
            o[j] = (n < NC) ? f2bf(Wout[k * NC + n]) : (unsigned short)0;
        }
    }
    unsigned short* dst = frag + (size_t)g * 512 + lane * 8;
    *((ushort4*)dst)       = *(ushort4*)&o[0];
    *((ushort4*)(dst + 4)) = *(ushort4*)&o[4];
}

// ---------------- X = relu(x @ W0 + b0); Xbf = X0bf = bf16(X) -----------------
__global__ __launch_bounds__(256) void gemm0_kernel(const float* __restrict__ x,
                                                    const float* __restrict__ W0,
                                                    const float* __restrict__ b0,
                                                    unsigned short* __restrict__ Xbf,
                                                    unsigned short* __restrict__ X0bf) {
    __shared__ float w[NF * NH];
    __shared__ float xr[16][NF + 4];
    const int tid = threadIdx.x;
    const int l16 = tid & 15;
    const int r   = tid >> 4;
    for (int i = tid; i < NF * NH; i += 256) w[i] = W0[i];
    const int row = blockIdx.x * 16 + r;      // grid = NV/16 exact
    float4 a0 = *((const float4*)(x + (size_t)row * NF) + l16);
    float4 a1 = *((const float4*)(x + (size_t)row * NF + 64) + l16);
    *((float4*)&xr[r][0] + l16)  = a0;
    *((float4*)&xr[r][64] + l16) = a1;
    __syncthreads();
    float4 acc = *((const float4*)b0 + l16);
#pragma unroll 8
    for (int j = 0; j < NF; ++j) {
        float xj = xr[r][j];
        float4 wv = *((const float4*)&w[j * NH] + l16);
        acc.x += xj * wv.x; acc.y += xj * wv.y;
        acc.z += xj * wv.z; acc.w += xj * wv.w;
    }
    acc.x = acc.x > 0.f ? acc.x : 0.f;
    acc.y = acc.y > 0.f ? acc.y : 0.f;
    acc.z = acc.z > 0.f ? acc.z : 0.f;
    acc.w = acc.w > 0.f ? acc.w : 0.f;
    ushort4 p = pack4(acc.x, acc.y, acc.z, acc.w);
    *((ushort4*)(Xbf  + (size_t)row * NH) + l16) = p;
    *((ushort4*)(X0bf + (size_t)row * NH) + l16) = p;
}

// ---------------- v->e gather -------------------------------------------------
__global__ __launch_bounds__(256) void gather_ve(const int* __restrict__ rs_e,
                                                 const int* __restrict__ vid_sorted,
                                                 const unsigned short* __restrict__ Xbf,
                                                 const float* __restrict__ scaleE,
                                                 unsigned short* __restrict__ Xebf) {
    const int tid = threadIdx.x;
    const int l16 = tid & 15;
    const int e = blockIdx.x * 16 + (tid >> 4);   // grid = NE/16 exact
    const int b  = rs_e[e];
    const int en = rs_e[e + 1];
    const float s = scaleE[e];
    float ax = 0.f, ay = 0.f, az = 0.f, aw = 0.f;
    int m = b;
    if (m + 4 <= en) {
        int i0 = vid_sorted[m], i1 = vid_sorted[m + 1];
        int i2 = vid_sorted[m + 2], i3 = vid_sorted[m + 3];
        m += 4;
        while (m + 4 <= en) {
            int j0 = vid_sorted[m], j1 = vid_sorted[m + 1];
            int j2 = vid_sorted[m + 2], j3 = vid_sorted[m + 3];
            m += 4;
            ushort4 p = *((const ushort4*)(Xbf + (size_t)i0 * NH) + l16);
            ushort4 q = *((const ushort4*)(Xbf + (size_t)i1 * NH) + l16);
            ushort4 u = *((const ushort4*)(Xbf + (size_t)i2 * NH) + l16);
            ushort4 t = *((const ushort4*)(Xbf + (size_t)i3 * NH) + l16);
            ax += bf2f(p.x) + bf2f(q.x) + bf2f(u.x) + bf2f(t.x);
            ay += bf2f(p.y) + bf2f(q.y) + bf2f(u.y) + bf2f(t.y);
            az += bf2f(p.z) + bf2f(q.z) + bf2f(u.z) + bf2f(t.z);
            aw += bf2f(p.w) + bf2f(q.w) + bf2f(u.w) + bf2f(t.w);
            i0 = j0; i1 = j1; i2 = j2; i3 = j3;
        }
        ushort4 p = *((const ushort4*)(Xbf + (size_t)i0 * NH) + l16);
        ushort4 q = *((const ushort4*)(Xbf + (size_t)i1 * NH) + l16);
        ushort4 u = *((const ushort4*)(Xbf + (size_t)i2 * NH) + l16);
        ushort4 t = *((const ushort4*)(Xbf + (size_t)i3 * NH) + l16);
        ax += bf2f(p.x) + bf2f(q.x) + bf2f(u.x) + bf2f(t.x);
        ay += bf2f(p.y) + bf2f(q.y) + bf2f(u.y) + bf2f(t.y);
        az += bf2f(p.z) + bf2f(q.z) + bf2f(u.z) + bf2f(t.z);
        aw += bf2f(p.w) + bf2f(q.w) + bf2f(u.w) + bf2f(t.w);
    }
    for (; m < en; ++m) {
        ushort4 p = *((const ushort4*)(Xbf + (size_t)vid_sorted[m] * NH) + l16);
        ax += bf2f(p.x); ay += bf2f(p.y); az += bf2f(p.z); aw += bf2f(p.w);
    }
    *((ushort4*)(Xebf + (size_t)e * NH) + l16) = pack4(ax * s, ay * s, az * s, aw * s);
}

// ---------------- e->v gather + normalize/residual + MFMA MLP (+head) ----------
template <bool LAST>
__global__ __launch_bounds__(256) void gather_ev_update(const int* __restrict__ rs_v,
                                                        const int* __restrict__ eid_sorted,
                                                        const unsigned short* __restrict__ Xebf,
                                                        const float* __restrict__ degV,
                                                        const unsigned short* __restrict__ X0bf,
                                                        const unsigned short* __restrict__ WfragL,
                                                        unsigned short* __restrict__ Xbf,
                                                        float beta,
                                                        const unsigned short* __restrict__ WfragH,
                                                        const float* __restrict__ bout,
                                                        float* __restrict__ outp) {
    __shared__ unsigned short xis_bf[16][72];              // bf16, stride 72 (2-way only)
    __shared__ unsigned short xo_bf[LAST ? 16 * 72 : 1];   // final X (LAST only)
    __shared__ float lg[LAST ? 16 * 48 : 1];               // logits (LAST only)
    const int tid = threadIdx.x;
    const int l16 = tid & 15;
    const int r   = tid >> 4;
    const int v = blockIdx.x * 16 + r;        // grid = NV/16 exact
    const int b  = rs_v[v];
    const int en = rs_v[v + 1];
    const float dv = degV[v];
    float ax = 0.f, ay = 0.f, az = 0.f, aw = 0.f;
    int m = b;
    if (m + 4 <= en) {
        int i0 = eid_sorted[m], i1 = eid_sorted[m + 1];
        int i2 = eid_sorted[m + 2], i3 = eid_sorted[m + 3];
        m += 4;
        while (m + 4 <= en) {
            int j0 = eid_sorted[m], j1 = eid_sorted[m + 1];
            int j2 = eid_sorted[m + 2], j3 = eid_sorted[m + 3];
            m += 4;
            ushort4 p = *((const ushort4*)(Xebf + (size_t)i0 * NH) + l16);
            ushort4 q = *((const ushort4*)(Xebf + (size_t)i1 * NH) + l16);
            ushort4 u = *((const ushort4*)(Xebf + (size_t)i2 * NH) + l16);
            ushort4 t = *((const ushort4*)(Xebf + (size_t)i3 * NH) + l16);
            ax += bf2f(p.x) + bf2f(q.x) + bf2f(u.x) + bf2f(t.x);
            ay += bf2f(p.y) + bf2f(q.y) + bf2f(u.y) + bf2f(t.y);
            az += bf2f(p.z) + bf2f(q.z) + bf2f(u.z) + bf2f(t.z);
            aw += bf2f(p.w) + bf2f(q.w) + bf2f(u.w) + bf2f(t.w);
            i0 = j0; i1 = j1; i2 = j2; i3 = j3;
        }
        ushort4 p = *((const ushort4*)(Xebf + (size_t)i0 * NH) + l16);
        ushort4 q = *((const ushort4*)(Xebf + (size_t)i1 * NH) + l16);
        ushort4 u = *((const ushort4*)(Xebf + (size_t)i2 * NH) + l16);
        ushort4 t = *((const ushort4*)(Xebf + (size_t)i3 * NH) + l16);
        ax += bf2f(p.x) + bf2f(q.x) + bf2f(u.x) + bf2f(t.x);
        ay += bf2f(p.y) + bf2f(q.y) + bf2f(u.y) + bf2f(t.y);
        az += bf2f(p.z) + bf2f(q.z) + bf2f(u.z) + bf2f(t.z);
        aw += bf2f(p.w) + bf2f(q.w) + bf2f(u.w) + bf2f(t.w);
    }
    for (; m < en; ++m) {
        ushort4 p = *((const ushort4*)(Xebf + (size_t)eid_sorted[m] * NH) + l16);
        ax += bf2f(p.x); ay += bf2f(p.y); az += bf2f(p.z); aw += bf2f(p.w);
    }
    ax *= dv; ay *= dv; az *= dv; aw *= dv;
    float sq = ax * ax + ay * ay + az * az + aw * aw;
#pragma unroll
    for (int o = 1; o < 16; o <<= 1) sq += __shfl_xor(sq, o);
    float norm = sqrtf(sq);
    float inv = norm > 0.f ? 1.f / norm : 0.f;
    ushort4 u0 = *((const ushort4*)(X0bf + (size_t)v * NH) + l16);
    float xi0 = 0.9f * ax * inv + 0.1f * bf2f(u0.x);
    float xi1 = 0.9f * ay * inv + 0.1f * bf2f(u0.y);
    float xi2 = 0.9f * az * inv + 0.1f * bf2f(u0.z);
    float xi3 = 0.9f * aw * inv + 0.1f * bf2f(u0.w);
    *((ushort4*)&xis_bf[r][l16 * 4]) = pack4(xi0, xi1, xi2, xi3);
    __syncthreads();

    // ---- MFMA MLP: g = xi @ Wl  (M=16, N=64, K=64) ----
    const int lane = tid & 63;
    const int wv   = tid >> 6;
    const int quad = lane >> 4;
    const int cl   = lane & 15;
    bf16x8 bw0 = *((const bf16x8*)(WfragL + ((size_t)(wv * 2 + 0) * 64 + lane) * 8));
    bf16x8 bw1 = *((const bf16x8*)(WfragL + ((size_t)(wv * 2 + 1) * 64 + lane) * 8));
    bf16x8 a0 = *((const bf16x8*)&xis_bf[cl][quad * 8]);
    bf16x8 a1 = *((const bf16x8*)&xis_bf[cl][32 + quad * 8]);
    f32x4 acc = {0.f, 0.f, 0.f, 0.f};
    acc = __builtin_amdgcn_mfma_f32_16x16x32_bf16(a0, bw0, acc, 0, 0, 0);
    acc = __builtin_amdgcn_mfma_f32_16x16x32_bf16(a1, bw1, acc, 0, 0, 0);

    const float ob = 1.f - beta;
    const int col = wv * 16 + cl;
#pragma unroll
    for (int p = 0; p < 4; ++p) {
        const int row = quad * 4 + p;
        float xiv = bf2f(xis_bf[row][col]);
        float o = ob * xiv + beta * acc[p];
        o = o > 0.f ? o : 0.f;
        if (!LAST) {
            Xbf[(size_t)(blockIdx.x * 16 + row) * NH + col] = f2bf(o);
        } else {
            xo_bf[row * 72 + col] = f2bf(o);
        }
    }
    if (LAST) {
        __syncthreads();
        // ---- MFMA output head: logits = Xfinal @ Wout (N padded to 64) ----
        bf16x8 bh0 = *((const bf16x8*)(WfragH + ((size_t)(wv * 2 + 0) * 64 + lane) * 8));
        bf16x8 bh1 = *((const bf16x8*)(WfragH + ((size_t)(wv * 2 + 1) * 64 + lane) * 8));
        bf16x8 ah0 = *((const bf16x8*)&xo_bf[cl * 72 + quad * 8]);
        bf16x8 ah1 = *((const bf16x8*)&xo_bf[cl * 72 + 32 + quad * 8]);
        f32x4 acch = {0.f, 0.f, 0.f, 0.f};
        acch = __builtin_amdgcn_mfma_f32_16x16x32_bf16(ah0, bh0, acch, 0, 0, 0);
        acch = __builtin_amdgcn_mfma_f32_16x16x32_bf16(ah1, bh1, acch, 0, 0, 0);
        if (col < NC) {
            float bo = bout[col];
#pragma unroll
            for (int p = 0; p < 4; ++p) lg[(quad * 4 + p) * 48 + col] = acch[p] + bo;
        }
        __syncthreads();
        // ---- log_softmax: each wave handles 4 rows ----
        const int r0 = wv * 4;
        const bool act = lane < NC;
        float a0s = act ? lg[(r0 + 0) * 48 + lane] : -INFINITY;
        float a1s = act ? lg[(r0 + 1) * 48 + lane] : -INFINITY;
        float a2s = act ? lg[(r0 + 2) * 48 + lane] : -INFINITY;
        float a3s = act ? lg[(r0 + 3) * 48 + lane] : -INFINITY;
        float m0 = a0s, m1 = a1s, m2 = a2s, m3 = a3s;
#pragma unroll
        for (int o = 32; o; o >>= 1) {
            m0 = fmaxf(m0, __shfl_xor(m0, o));
            m1 = fmaxf(m1, __shfl_xor(m1, o));
            m2 = fmaxf(m2, __shfl_xor(m2, o));
            m3 = fmaxf(m3, __shfl_xor(m3, o));
        }
        float e0 = act ? expf(a0s - m0) : 0.f;
        float e1 = act ? expf(a1s - m1) : 0.f;
        float e2 = act ? expf(a2s - m2) : 0.f;
        float e3 = act ? expf(a3s - m3) : 0.f;
#pragma unroll
        for (int o = 32; o; o >>= 1) {
            e0 += __shfl_xor(e0, o);
            e1 += __shfl_xor(e1, o);
            e2 += __shfl_xor(e2, o);
            e3 += __shfl_xor(e3, o);
        }
        if (act) {
            const size_t vb = (size_t)(blockIdx.x * 16 + r0) * NC + lane;
            outp[vb + 0 * NC] = a0s - m0 - logf(e0);
            outp[vb + 1 * NC] = a1s - m1 - logf(e1);
            outp[vb + 2 * NC] = a2s - m2 - logf(e2);
            outp[vb + 3 * NC] = a3s - m3 - logf(e3);
        }
    }
}

extern "C" void kernel_launch(void* const* d_in, const int* in_sizes, int n_in,
                              void* d_out, int out_size, void* d_ws, size_t ws_size,
                              hipStream_t stream) {
    const float* x    = (const float*)d_in[0];
    const float* degE = (const float*)d_in[1];
    const float* degV = (const float*)d_in[2];
    const float* W0   = (const float*)d_in[3];
    const float* b0   = (const float*)d_in[4];
    const float* Ws   = (const float*)d_in[5];
    const float* Wout = (const float*)d_in[6];
    const float* bout = (const float*)d_in[7];
    const int* vertex = (const int*)d_in[8];
    const int* edges  = (const int*)d_in[9];
    float* out = (float*)d_out;

    // workspace layout
    float* scaleE = (float*)d_ws;                              // NEg
    unsigned short* Xbf  = (unsigned short*)(scaleE + NEg);    // NV*NH bf16
    unsigned short* X0bf = Xbf + (size_t)NV * NH;
    unsigned short* Xebf = X0bf + (size_t)NV * NH;             // NE*NH bf16
    int* cnt_be = (int*)(Xebf + (size_t)NEg * NH);
    int* cnt_bv = cnt_be + NBE;
    int* gcur_e = cnt_bv + NBV;
    int* gcur_v = gcur_e + NBE;
    int* rsb_e  = gcur_v + NBV;
    int* rsb_v  = rsb_e + (NBE + 1);
    int* rs_e   = rsb_v + (NBV + 1);
    int* rs_v   = rs_e + (NEg + 1);
    int* vid_sorted = rs_v + (NV + 1);                         // NNZ
    int* eid_sorted = vid_sorted + NNZp;                       // NNZ
    unsigned short* Wfrag = (unsigned short*)(eid_sorted + NNZp);  // 40 groups * 512

    // ---- CSR build + weight fragments ----
    hipMemsetAsync(cnt_be, 0, (size_t)(NBE + NBV) * 2 * sizeof(int), stream);
    make_wfrag<<<10, 256, 0, stream>>>(Ws, Wout, Wfrag);
    coarse_hist<<<PBLK, 256, 0, stream>>>(vertex, edges, cnt_be, cnt_bv);
    scan_buckets<<<2, 512, 0, stream>>>(cnt_be, cnt_bv, rsb_e, rsb_v, rs_e, rs_v);
    partition_both<<<PBLK, 256, 0, stream>>>(vertex, edges, rsb_e, rsb_v,
                                             gcur_e, gcur_v, vid_sorted, eid_sorted);
    local_sort_both<<<NBE + NBV, 512, 0, stream>>>(rsb_e, rsb_v, vid_sorted, eid_sorted,
                                                   rs_e, rs_v, degE, scaleE);

    // ---- X = relu(x @ W0 + b0) ----
    gemm0_kernel<<<NV / 16, 256, 0, stream>>>(x, W0, b0, Xbf, X0bf);

    const float betas[4] = {logf(0.5f / 1.f + 1.f), logf(0.5f / 2.f + 1.f),
                            logf(0.5f / 3.f + 1.f), logf(0.5f / 4.f + 1.f)};

    for (int i = 0; i < 3; ++i) {
        gather_ve<<<NEg / 16, 256, 0, stream>>>(rs_e, vid_sorted, Xbf, scaleE, Xebf);
        gather_ev_update<false><<<NV / 16, 256, 0, stream>>>(rs_v, eid_sorted, Xebf, degV,
                                                             X0bf, Wfrag + (size_t)i * 4096,
                                                             Xbf, betas[i],
                                                             nullptr, nullptr, nullptr);
    }
    gather_ve<<<NEg / 16, 256, 0, stream>>>(rs_e, vid_sorted, Xbf, scaleE, Xebf);
    gather_ev_update<true><<<NV / 16, 256, 0, stream>>>(rs_v, eid_sorted, Xebf, degV,
                                                        X0bf, Wfrag + (size_t)3 * 4096,
                                                        Xbf, betas[3],
                                                        Wfrag + 16384, bout, out);
}

// Round 9
// 451.004 us; speedup vs baseline: 7.5493x; 1.0708x over previous
//
#include <hip/hip_runtime.h>
#include <math.h>

constexpr int NV   = 100000;
constexpr int NEg  = 20000;
constexpr int NNZp = 1600000;
constexpr int NF   = 128;
constexpr int NH   = 64;
constexpr int NC   = 40;

constexpr int WE  = 64;                       // e-bucket width (2^6)
constexpr int NBE = (NEg + WE - 1) / WE;      // 313
constexpr int WV  = 256;                      // v-bucket width (2^8)
constexpr int NBV = (NV + WV - 1) / WV;       // 391
constexpr int CAPS = 6400;                    // local_sort stage cap
constexpr int CH   = 2048;                    // partition chunk per block
constexpr int PBLK = (NNZp + CH - 1) / CH;    // 782

typedef __bf16 bf16x8 __attribute__((ext_vector_type(8)));
typedef float  f32x4  __attribute__((ext_vector_type(4)));

// ---- bf16 <-> fp32 helpers (RNE) ----
__device__ __forceinline__ float bf2f(unsigned short u) {
    unsigned int x = ((unsigned int)u) << 16;
    return __builtin_bit_cast(float, x);
}
__device__ __forceinline__ unsigned short f2bf(float f) {
    unsigned int x = __builtin_bit_cast(unsigned int, f);
    x += 0x7fffu + ((x >> 16) & 1u);
    return (unsigned short)(x >> 16);
}
__device__ __forceinline__ ushort4 pack4(float a, float b, float c, float d) {
    ushort4 u; u.x = f2bf(a); u.y = f2bf(b); u.z = f2bf(c); u.w = f2bf(d);
    return u;
}

// ---------------- coarse histograms ----------------
__global__ __launch_bounds__(256) void coarse_hist(const int* __restrict__ vertex,
                                                   const int* __restrict__ edges,
                                                   int* __restrict__ cnt_be,
                                                   int* __restrict__ cnt_bv) {
    __shared__ int he[NBE], hv[NBV];
    for (int i = threadIdx.x; i < NBE; i += 256) he[i] = 0;
    for (int i = threadIdx.x; i < NBV; i += 256) hv[i] = 0;
    __syncthreads();
    const int base = blockIdx.x * CH;
    const int end  = min(base + CH, NNZp);
    for (int i = base + threadIdx.x; i < end; i += 256) {
        atomicAdd(&he[edges[i]  >> 6], 1);
        atomicAdd(&hv[vertex[i] >> 8], 1);
    }
    __syncthreads();
    for (int i = threadIdx.x; i < NBE; i += 256) if (he[i]) atomicAdd(&cnt_be[i], he[i]);
    for (int i = threadIdx.x; i < NBV; i += 256) if (hv[i]) atomicAdd(&cnt_bv[i], hv[i]);
}

// ---------------- tiny bucket scans ----------------
__global__ __launch_bounds__(512) void scan_buckets(const int* __restrict__ cnt_be,
                                                    const int* __restrict__ cnt_bv,
                                                    int* __restrict__ rsb_e,
                                                    int* __restrict__ rsb_v,
                                                    int* __restrict__ rs_e,
                                                    int* __restrict__ rs_v) {
    __shared__ int s[512];
    const int n      = (blockIdx.x == 0) ? NBE : NBV;
    const int* c     = (blockIdx.x == 0) ? cnt_be : cnt_bv;
    int* r           = (blockIdx.x == 0) ? rsb_e : rsb_v;
    const int t = threadIdx.x;
    int v = (t < n) ? c[t] : 0;
    s[t] = v;
    __syncthreads();
    for (int o = 1; o < 512; o <<= 1) {
        int u = (t >= o) ? s[t - o] : 0;
        __syncthreads();
        s[t] += u;
        __syncthreads();
    }
    if (t < n) r[t] = s[t] - v;
    if (t == 0) {
        r[n] = NNZp;
        if (blockIdx.x == 0) rs_e[NEg] = NNZp;
        else                 rs_v[NV]  = NNZp;
    }
}

// ------- fused partition: both sides, indices staged in LDS -------------------
__global__ __launch_bounds__(256) void partition_both(const int* __restrict__ vertex,
                                                      const int* __restrict__ edges,
                                                      const int* __restrict__ rsb_e,
                                                      const int* __restrict__ rsb_v,
                                                      int* __restrict__ gcur_e,
                                                      int* __restrict__ gcur_v,
                                                      int* __restrict__ vid_out,
                                                      int* __restrict__ eid_out) {
    __shared__ int se[CH], sv[CH];
    __shared__ int cur_e[NBE], cur_v[NBV];
    const int tid = threadIdx.x;
    for (int i = tid; i < NBE; i += 256) cur_e[i] = 0;
    for (int i = tid; i < NBV; i += 256) cur_v[i] = 0;
    __syncthreads();
    const int base = blockIdx.x * CH;
    const int n    = min(base + CH, NNZp) - base;
    for (int i = tid; i < n; i += 256) {
        int e = edges[base + i];
        int v = vertex[base + i];
        se[i] = e; sv[i] = v;
        atomicAdd(&cur_e[e >> 6], 1);
        atomicAdd(&cur_v[v >> 8], 1);
    }
    __syncthreads();
    for (int i = tid; i < NBE; i += 256) {
        int h = cur_e[i];
        cur_e[i] = rsb_e[i] + (h ? atomicAdd(&gcur_e[i], h) : 0);
    }
    for (int i = tid; i < NBV; i += 256) {
        int h = cur_v[i];
        cur_v[i] = rsb_v[i] + (h ? atomicAdd(&gcur_v[i], h) : 0);
    }
    __syncthreads();
    for (int i = tid; i < n; i += 256) {
        int e = se[i], v = sv[i];
        int pe = atomicAdd(&cur_e[e >> 6], 1);
        vid_out[pe] = (v << 6) | (e & 63);
        int pv = atomicAdd(&cur_v[v >> 8], 1);
        eid_out[pv] = (e << 8) | (v & 255);
    }
}

// ------- fused per-bucket LDS counting sort -----------------------------------
__global__ __launch_bounds__(512) void local_sort_both(const int* __restrict__ rsb_e,
                                                       const int* __restrict__ rsb_v,
                                                       int* __restrict__ vid_buf,
                                                       int* __restrict__ eid_buf,
                                                       int* __restrict__ rs_e,
                                                       int* __restrict__ rs_v,
                                                       const float* __restrict__ degE,
                                                       float* __restrict__ scaleE) {
    __shared__ int stage[CAPS];
    __shared__ int hist[256], off[256], cnt2[256];
    const bool eside = blockIdx.x < NBE;
    const int b   = eside ? blockIdx.x : blockIdx.x - NBE;
    const int W   = eside ? 64 : 256;
    const int FB  = eside ? 6 : 8;
    const int NID = eside ? NEg : NV;
    const int* rsb = eside ? rsb_e : rsb_v;
    int* buf       = eside ? vid_buf : eid_buf;
    int* rs        = eside ? rs_e : rs_v;
    const int base = rsb[b];
    const int sz   = rsb[b + 1] - base;
    const int tid = threadIdx.x;
    if (tid < 256) { hist[tid] = 0; cnt2[tid] = 0; }
    __syncthreads();
    for (int t = tid; t < sz; t += 512) atomicAdd(&hist[buf[base + t] & (W - 1)], 1);
    __syncthreads();
    {
        int v = (tid < W) ? hist[tid] : 0;
        if (tid < W) off[tid] = v;
        __syncthreads();
        for (int o = 1; o < W; o <<= 1) {
            int u = (tid < W && tid >= o) ? off[tid - o] : 0;
            __syncthreads();
            if (tid < W) off[tid] += u;
            __syncthreads();
        }
        if (tid < W) off[tid] -= v;
    }
    if (tid < W) {
        int gid = b * W + tid;
        if (gid < NID) {
            rs[gid] = base + off[tid];
            if (eside) {
                int c = hist[tid];
                scaleE[gid] = degE[gid] / (float)(c < 1 ? 1 : c);
            }
        }
    }
    __syncthreads();
    for (int t = tid; t < sz; t += 512) {
        int w = buf[base + t];
        int f = w & (W - 1);
        int rk = off[f] + atomicAdd(&cnt2[f], 1);
        stage[rk] = w >> FB;
    }
    __syncthreads();
    for (int t = tid; t < sz; t += 512) buf[base + t] = stage[t];
}

// ------- W fragments (B-operand layout, bf16): Ws MLPs + head + W0 ------------
// g<32:        layer MLPs,  g=((layer*4+wave)*2+khalf), K=64
// g in 32..39: output head, g=32+wave*2+khalf, N cols >=NC zero-padded
// g in 40..55: W0 (K=128),  g=40+wave*4+kblock
__global__ __launch_bounds__(256) void make_wfrag(const float* __restrict__ Ws,
                                                  const float* __restrict__ Wout,
                                                  const float* __restrict__ W0,
                                                  unsigned short* __restrict__ frag) {
    int t = blockIdx.x * 256 + threadIdx.x;     // 3584 threads exactly
    int lane = t & 63;
    int g = t >> 6;                             // 0..55
    int quad = lane >> 4, cl = lane & 15;
    unsigned short o[8];
    if (g < 32) {
        int li = g >> 3, w = (g >> 1) & 3, kh = g & 1;
        int n = w * 16 + cl;
#pragma unroll
        for (int j = 0; j < 8; ++j) {
            int k = kh * 32 + quad * 8 + j;
            o[j] = f2bf(Ws[(size_t)li * NH * NH + k * NH + n]);
        }
    } else if (g < 40) {
        int w = (g - 32) >> 1, kh = g & 1;
        int n = w * 16 + cl;
#pragma unroll
        for (int j = 0; j < 8; ++j) {
            int k = kh * 32 + quad * 8 + j;
            o[j] = (n < NC) ? f2bf(Wout[k * NC + n]) : (unsigned short)0;
        }
    } else {
        int w = (g - 40) >> 2, kb = (g - 40) & 3;
        int n = w * 16 + cl;
#pragma unroll
        for (int j = 0; j < 8; ++j) {
            int k = kb * 32 + quad * 8 + j;
            o[j] = f2bf(W0[k * NH + n]);
        }
    }
    unsigned short* dst = frag + (size_t)g * 512 + lane * 8;
    *((ushort4*)dst)       = *(ushort4*)&o[0];
    *((ushort4*)(dst + 4)) = *(ushort4*)&o[4];
}

// ---------------- X = relu(x @ W0 + b0) via MFMA; Xbf = X0bf ------------------
__global__ __launch_bounds__(256) void gemm0_kernel(const float* __restrict__ x,
                                                    const unsigned short* __restrict__ W0frag,
                                                    const float* __restrict__ b0,
                                                    unsigned short* __restrict__ Xbf,
                                                    unsigned short* __restrict__ X0bf) {
    __shared__ unsigned short xs[16][136];    // bf16, stride 136 (16B-aligned rows)
    const int tid = threadIdx.x;
    const int r  = tid >> 4;
    const int c8 = (tid & 15) * 8;
    const int rowbase = blockIdx.x * 16;      // grid = NV/16 exact
    float4 p0 = *((const float4*)(x + (size_t)(rowbase + r) * NF + c8));
    float4 p1 = *((const float4*)(x + (size_t)(rowbase + r) * NF + c8 + 4));
    *((ushort4*)&xs[r][c8])     = pack4(p0.x, p0.y, p0.z, p0.w);
    *((ushort4*)&xs[r][c8 + 4]) = pack4(p1.x, p1.y, p1.z, p1.w);
    __syncthreads();
    const int lane = tid & 63;
    const int wv   = tid >> 6;
    const int quad = lane >> 4;
    const int cl   = lane & 15;
    f32x4 acc = {0.f, 0.f, 0.f, 0.f};
#pragma unroll
    for (int kb = 0; kb < 4; ++kb) {
        bf16x8 a = *((const bf16x8*)&xs[cl][kb * 32 + quad * 8]);
        bf16x8 b = *((const bf16x8*)(W0frag + ((size_t)(wv * 4 + kb) * 64 + lane) * 8));
        acc = __builtin_amdgcn_mfma_f32_16x16x32_bf16(a, b, acc, 0, 0, 0);
    }
    const int col = wv * 16 + cl;
    const float bo = b0[col];
#pragma unroll
    for (int p = 0; p < 4; ++p) {
        const int orow = quad * 4 + p;
        float o = acc[p] + bo;
        o = o > 0.f ? o : 0.f;
        unsigned short ob = f2bf(o);
        const size_t idx = (size_t)(rowbase + orow) * NH + col;
        Xbf[idx]  = ob;
        X0bf[idx] = ob;
    }
}

// ---------------- v->e gather -------------------------------------------------
__global__ __launch_bounds__(256) void gather_ve(const int* __restrict__ rs_e,
                                                 const int* __restrict__ vid_sorted,
                                                 const unsigned short* __restrict__ Xbf,
                                                 const float* __restrict__ scaleE,
                                                 unsigned short* __restrict__ Xebf) {
    const int tid = threadIdx.x;
    const int l16 = tid & 15;
    const int e = blockIdx.x * 16 + (tid >> 4);   // grid = NE/16 exact
    const int b  = rs_e[e];
    const int en = rs_e[e + 1];
    const float s = scaleE[e];
    float ax = 0.f, ay = 0.f, az = 0.f, aw = 0.f;
    int m = b;
    if (m + 4 <= en) {
        int i0 = vid_sorted[m], i1 = vid_sorted[m + 1];
        int i2 = vid_sorted[m + 2], i3 = vid_sorted[m + 3];
        m += 4;
        while (m + 4 <= en) {
            int j0 = vid_sorted[m], j1 = vid_sorted[m + 1];
            int j2 = vid_sorted[m + 2], j3 = vid_sorted[m + 3];
            m += 4;
            ushort4 p = *((const ushort4*)(Xbf + (size_t)i0 * NH) + l16);
            ushort4 q = *((const ushort4*)(Xbf + (size_t)i1 * NH) + l16);
            ushort4 u = *((const ushort4*)(Xbf + (size_t)i2 * NH) + l16);
            ushort4 t = *((const ushort4*)(Xbf + (size_t)i3 * NH) + l16);
            ax += bf2f(p.x) + bf2f(q.x) + bf2f(u.x) + bf2f(t.x);
            ay += bf2f(p.y) + bf2f(q.y) + bf2f(u.y) + bf2f(t.y);
            az += bf2f(p.z) + bf2f(q.z) + bf2f(u.z) + bf2f(t.z);
            aw += bf2f(p.w) + bf2f(q.w) + bf2f(u.w) + bf2f(t.w);
            i0 = j0; i1 = j1; i2 = j2; i3 = j3;
        }
        ushort4 p = *((const ushort4*)(Xbf + (size_t)i0 * NH) + l16);
        ushort4 q = *((const ushort4*)(Xbf + (size_t)i1 * NH) + l16);
        ushort4 u = *((const ushort4*)(Xbf + (size_t)i2 * NH) + l16);
        ushort4 t = *((const ushort4*)(Xbf + (size_t)i3 * NH) + l16);
        ax += bf2f(p.x) + bf2f(q.x) + bf2f(u.x) + bf2f(t.x);
        ay += bf2f(p.y) + bf2f(q.y) + bf2f(u.y) + bf2f(t.y);
        az += bf2f(p.z) + bf2f(q.z) + bf2f(u.z) + bf2f(t.z);
        aw += bf2f(p.w) + bf2f(q.w) + bf2f(u.w) + bf2f(t.w);
    }
    for (; m < en; ++m) {
        ushort4 p = *((const ushort4*)(Xbf + (size_t)vid_sorted[m] * NH) + l16);
        ax += bf2f(p.x); ay += bf2f(p.y); az += bf2f(p.z); aw += bf2f(p.w);
    }
    *((ushort4*)(Xebf + (size_t)e * NH) + l16) = pack4(ax * s, ay * s, az * s, aw * s);
}

// ---------------- e->v gather + normalize/residual + MFMA MLP (+head) ----------
template <bool LAST>
__global__ __launch_bounds__(256) void gather_ev_update(const int* __restrict__ rs_v,
                                                        const int* __restrict__ eid_sorted,
                                                        const unsigned short* __restrict__ Xebf,
                                                        const float* __restrict__ degV,
                                                        const unsigned short* __restrict__ X0bf,
                                                        const unsigned short* __restrict__ WfragL,
                                                        unsigned short* __restrict__ Xbf,
                                                        float beta,
                                                        const unsigned short* __restrict__ WfragH,
                                                        const float* __restrict__ bout,
                                                        float* __restrict__ outp) {
    __shared__ unsigned short xis_bf[16][72];              // bf16, stride 72 (2-way only)
    __shared__ unsigned short xo_bf[LAST ? 16 * 72 : 1];   // final X (LAST only)
    __shared__ float lg[LAST ? 16 * 48 : 1];               // logits (LAST only)
    const int tid = threadIdx.x;
    const int l16 = tid & 15;
    const int r   = tid >> 4;
    const int v = blockIdx.x * 16 + r;        // grid = NV/16 exact
    const int b  = rs_v[v];
    const int en = rs_v[v + 1];
    const float dv = degV[v];
    float ax = 0.f, ay = 0.f, az = 0.f, aw = 0.f;
    int m = b;
    if (m + 4 <= en) {
        int i0 = eid_sorted[m], i1 = eid_sorted[m + 1];
        int i2 = eid_sorted[m + 2], i3 = eid_sorted[m + 3];
        m += 4;
        while (m + 4 <= en) {
            int j0 = eid_sorted[m], j1 = eid_sorted[m + 1];
            int j2 = eid_sorted[m + 2], j3 = eid_sorted[m + 3];
            m += 4;
            ushort4 p = *((const ushort4*)(Xebf + (size_t)i0 * NH) + l16);
            ushort4 q = *((const ushort4*)(Xebf + (size_t)i1 * NH) + l16);
            ushort4 u = *((const ushort4*)(Xebf + (size_t)i2 * NH) + l16);
            ushort4 t = *((const ushort4*)(Xebf + (size_t)i3 * NH) + l16);
            ax += bf2f(p.x) + bf2f(q.x) + bf2f(u.x) + bf2f(t.x);
            ay += bf2f(p.y) + bf2f(q.y) + bf2f(u.y) + bf2f(t.y);
            az += bf2f(p.z) + bf2f(q.z) + bf2f(u.z) + bf2f(t.z);
            aw += bf2f(p.w) + bf2f(q.w) + bf2f(u.w) + bf2f(t.w);
            i0 = j0; i1 = j1; i2 = j2; i3 = j3;
        }
        ushort4 p = *((const ushort4*)(Xebf + (size_t)i0 * NH) + l16);
        ushort4 q = *((const ushort4*)(Xebf + (size_t)i1 * NH) + l16);
        ushort4 u = *((const ushort4*)(Xebf + (size_t)i2 * NH) + l16);
        ushort4 t = *((const ushort4*)(Xebf + (size_t)i3 * NH) + l16);
        ax += bf2f(p.x) + bf2f(q.x) + bf2f(u.x) + bf2f(t.x);
        ay += bf2f(p.y) + bf2f(q.y) + bf2f(u.y) + bf2f(t.y);
        az += bf2f(p.z) + bf2f(q.z) + bf2f(u.z) + bf2f(t.z);
        aw += bf2f(p.w) + bf2f(q.w) + bf2f(u.w) + bf2f(t.w);
    }
    for (; m < en; ++m) {
        ushort4 p = *((const ushort4*)(Xebf + (size_t)eid_sorted[m] * NH) + l16);
        ax += bf2f(p.x); ay += bf2f(p.y); az += bf2f(p.z); aw += bf2f(p.w);
    }
    ax *= dv; ay *= dv; az *= dv; aw *= dv;
    float sq = ax * ax + ay * ay + az * az + aw * aw;
#pragma unroll
    for (int o = 1; o < 16; o <<= 1) sq += __shfl_xor(sq, o);
    float norm = sqrtf(sq);
    float inv = norm > 0.f ? 1.f / norm : 0.f;
    ushort4 u0 = *((const ushort4*)(X0bf + (size_t)v * NH) + l16);
    float xi0 = 0.9f * ax * inv + 0.1f * bf2f(u0.x);
    float xi1 = 0.9f * ay * inv + 0.1f * bf2f(u0.y);
    float xi2 = 0.9f * az * inv + 0.1f * bf2f(u0.z);
    float xi3 = 0.9f * aw * inv + 0.1f * bf2f(u0.w);
    *((ushort4*)&xis_bf[r][l16 * 4]) = pack4(xi0, xi1, xi2, xi3);
    __syncthreads();

    // ---- MFMA MLP: g = xi @ Wl  (M=16, N=64, K=64) ----
    const int lane = tid & 63;
    const int wv   = tid >> 6;
    const int quad = lane >> 4;
    const int cl   = lane & 15;
    bf16x8 bw0 = *((const bf16x8*)(WfragL + ((size_t)(wv * 2 + 0) * 64 + lane) * 8));
    bf16x8 bw1 = *((const bf16x8*)(WfragL + ((size_t)(wv * 2 + 1) * 64 + lane) * 8));
    bf16x8 a0 = *((const bf16x8*)&xis_bf[cl][quad * 8]);
    bf16x8 a1 = *((const bf16x8*)&xis_bf[cl][32 + quad * 8]);
    f32x4 acc = {0.f, 0.f, 0.f, 0.f};
    acc = __builtin_amdgcn_mfma_f32_16x16x32_bf16(a0, bw0, acc, 0, 0, 0);
    acc = __builtin_amdgcn_mfma_f32_16x16x32_bf16(a1, bw1, acc, 0, 0, 0);

    const float ob = 1.f - beta;
    const int col = wv * 16 + cl;
#pragma unroll
    for (int p = 0; p < 4; ++p) {
        const int row = quad * 4 + p;
        float xiv = bf2f(xis_bf[row][col]);
        float o = ob * xiv + beta * acc[p];
        o = o > 0.f ? o : 0.f;
        if (!LAST) {
            Xbf[(size_t)(blockIdx.x * 16 + row) * NH + col] = f2bf(o);
        } else {
            xo_bf[row * 72 + col] = f2bf(o);
        }
    }
    if (LAST) {
        __syncthreads();
        // ---- MFMA output head: logits = Xfinal @ Wout (N padded to 64) ----
        bf16x8 bh0 = *((const bf16x8*)(WfragH + ((size_t)(wv * 2 + 0) * 64 + lane) * 8));
        bf16x8 bh1 = *((const bf16x8*)(WfragH + ((size_t)(wv * 2 + 1) * 64 + lane) * 8));
        bf16x8 ah0 = *((const bf16x8*)&xo_bf[cl * 72 + quad * 8]);
        bf16x8 ah1 = *((const bf16x8*)&xo_bf[cl * 72 + 32 + quad * 8]);
        f32x4 acch = {0.f, 0.f, 0.f, 0.f};
        acch = __builtin_amdgcn_mfma_f32_16x16x32_bf16(ah0, bh0, acch, 0, 0, 0);
        acch = __builtin_amdgcn_mfma_f32_16x16x32_bf16(ah1, bh1, acch, 0, 0, 0);
        if (col < NC) {
            float bo = bout[col];
#pragma unroll
            for (int p = 0; p < 4; ++p) lg[(quad * 4 + p) * 48 + col] = acch[p] + bo;
        }
        __syncthreads();
        // ---- log_softmax: each wave handles 4 rows ----
        const int r0 = wv * 4;
        const bool act = lane < NC;
        float a0s = act ? lg[(r0 + 0) * 48 + lane] : -INFINITY;
        float a1s = act ? lg[(r0 + 1) * 48 + lane] : -INFINITY;
        float a2s = act ? lg[(r0 + 2) * 48 + lane] : -INFINITY;
        float a3s = act ? lg[(r0 + 3) * 48 + lane] : -INFINITY;
        float m0 = a0s, m1 = a1s, m2 = a2s, m3 = a3s;
#pragma unroll
        for (int o = 32; o; o >>= 1) {
            m0 = fmaxf(m0, __shfl_xor(m0, o));
            m1 = fmaxf(m1, __shfl_xor(m1, o));
            m2 = fmaxf(m2, __shfl_xor(m2, o));
            m3 = fmaxf(m3, __shfl_xor(m3, o));
        }
        float e0 = act ? expf(a0s - m0) : 0.f;
        float e1 = act ? expf(a1s - m1) : 0.f;
        float e2 = act ? expf(a2s - m2) : 0.f;
        float e3 = act ? expf(a3s - m3) : 0.f;
#pragma unroll
        for (int o = 32; o; o >>= 1) {
            e0 += __shfl_xor(e0, o);
            e1 += __shfl_xor(e1, o);
            e2 += __shfl_xor(e2, o);
            e3 += __shfl_xor(e3, o);
        }
        if (act) {
            const size_t vb = (size_t)(blockIdx.x * 16 + r0) * NC + lane;
            outp[vb + 0 * NC] = a0s - m0 - logf(e0);
            outp[vb + 1 * NC] = a1s - m1 - logf(e1);
            outp[vb + 2 * NC] = a2s - m2 - logf(e2);
            outp[vb + 3 * NC] = a3s - m3 - logf(e3);
        }
    }
}

extern "C" void kernel_launch(void* const* d_in, const int* in_sizes, int n_in,
                              void* d_out, int out_size, void* d_ws, size_t ws_size,
                              hipStream_t stream) {
    const float* x    = (const float*)d_in[0];
    const float* degE = (const float*)d_in[1];
    const float* degV = (const float*)d_in[2];
    const float* W0   = (const float*)d_in[3];
    const float* b0   = (const float*)d_in[4];
    const float* Ws   = (const float*)d_in[5];
    const float* Wout = (const float*)d_in[6];
    const float* bout = (const float*)d_in[7];
    const int* vertex = (const int*)d_in[8];
    const int* edges  = (const int*)d_in[9];
    float* out = (float*)d_out;

    // workspace layout
    float* scaleE = (float*)d_ws;                              // NEg
    unsigned short* Xbf  = (unsigned short*)(scaleE + NEg);    // NV*NH bf16
    unsigned short* X0bf = Xbf + (size_t)NV * NH;
    unsigned short* Xebf = X0bf + (size_t)NV * NH;             // NE*NH bf16
    int* cnt_be = (int*)(Xebf + (size_t)NEg * NH);
    int* cnt_bv = cnt_be + NBE;
    int* gcur_e = cnt_bv + NBV;
    int* gcur_v = gcur_e + NBE;
    int* rsb_e  = gcur_v + NBV;
    int* rsb_v  = rsb_e + (NBE + 1);
    int* rs_e   = rsb_v + (NBV + 1);
    int* rs_v   = rs_e + (NEg + 1);
    int* vid_sorted = rs_v + (NV + 1);                         // NNZ
    int* eid_sorted = vid_sorted + NNZp;                       // NNZ
    unsigned short* Wfrag = (unsigned short*)(eid_sorted + NNZp);  // 56 groups * 512

    // ---- CSR build + weight fragments ----
    hipMemsetAsync(cnt_be, 0, (size_t)(NBE + NBV) * 2 * sizeof(int), stream);
    make_wfrag<<<14, 256, 0, stream>>>(Ws, Wout, W0, Wfrag);
    coarse_hist<<<PBLK, 256, 0, stream>>>(vertex, edges, cnt_be, cnt_bv);
    scan_buckets<<<2, 512, 0, stream>>>(cnt_be, cnt_bv, rsb_e, rsb_v, rs_e, rs_v);
    partition_both<<<PBLK, 256, 0, stream>>>(vertex, edges, rsb_e, rsb_v,
                                             gcur_e, gcur_v, vid_sorted, eid_sorted);
    local_sort_both<<<NBE + NBV, 512, 0, stream>>>(rsb_e, rsb_v, vid_sorted, eid_sorted,
                                                   rs_e, rs_v, degE, scaleE);

    // ---- X = relu(x @ W0 + b0) via MFMA ----
    gemm0_kernel<<<NV / 16, 256, 0, stream>>>(x, Wfrag + 40 * 512, b0, Xbf, X0bf);

    const float betas[4] = {logf(0.5f / 1.f + 1.f), logf(0.5f / 2.f + 1.f),
                            logf(0.5f / 3.f + 1.f), logf(0.5f / 4.f + 1.f)};

    for (int i = 0; i < 3; ++i) {
        gather_ve<<<NEg / 16, 256, 0, stream>>>(rs_e, vid_sorted, Xbf, scaleE, Xebf);
        gather_ev_update<false><<<NV / 16, 256, 0, stream>>>(rs_v, eid_sorted, Xebf, degV,
                                                             X0bf, Wfrag + (size_t)i * 4096,
                                                             Xbf, betas[i],
                                                             nullptr, nullptr, nullptr);
    }
    gather_ve<<<NEg / 16, 256, 0, stream>>>(rs_e, vid_sorted, Xbf, scaleE, Xebf);
    gather_ev_update<true><<<NV / 16, 256, 0, stream>>>(rs_v, eid_sorted, Xebf, degV,
                                                        X0bf, Wfrag + (size_t)3 * 4096,
                                                        Xbf, betas[3],
                                                        Wfrag + 16384, bout, out);
}